// Round 9
// baseline (1695.365 us; speedup 1.0000x reference)
//
#include <hip/hip_runtime.h>
#include <hip/hip_bf16.h>
#include <cstddef>
#include <cstdint>

#define D_MODEL 512
#define BATCH 16
#define EPS_LN 1e-5f

typedef __bf16 bf16x8 __attribute__((ext_vector_type(8)));
typedef float f32x4 __attribute__((ext_vector_type(4)));
typedef unsigned short u16x8 __attribute__((ext_vector_type(8)));
typedef unsigned short u16x4 __attribute__((ext_vector_type(4)));
typedef unsigned short u16x2 __attribute__((ext_vector_type(2)));

__device__ __forceinline__ void gload_lds16(const void* g, void* l) {
    __builtin_amdgcn_global_load_lds(
        (const __attribute__((address_space(1))) void*)g,
        (__attribute__((address_space(3))) void*)l,
        16, 0, 0);
}

// Bijective XCD swizzle (m204): groups consecutive tiles per XCD.
__device__ __forceinline__ int xcd_swz(int wg, int nwg) {
    const int q = nwg >> 3, r = nwg & 7;
    const int x = wg & 7, p = wg >> 3;
    return (x < r ? x * (q + 1) : r * (q + 1) + (x - r) * q) + p;
}

// ---------------------------------------------------------------------------
// MFMA bf16 NT GEMM, activations [b][s][*] (row r = b*S + s).
// Tile BM x 128, BK=64, 512 threads (8 waves, 2x4), double-buffered 2-phase.
// 1D grid with XCD-aware swizzle; gx = number of col-tiles.
// SWAP=1: swapped-operand epilogue -> vector stores, bf16, full tiles.
// SWAP=0: classic; col guard, VT side-output, dual bias, W split, permrow.
// ---------------------------------------------------------------------------
template <int BM, int OUTBF16, int SWAP>
__global__ __launch_bounds__(512) void gemm_mfma(
    const __bf16* __restrict__ A, const __bf16* __restrict__ W,
    const __bf16* __restrict__ W2, int wsplit,
    const float* __restrict__ bias, const float* __restrict__ bias2, int bsplit,
    void* __restrict__ Cout, __bf16* __restrict__ VTout, int m_vt0, int log2S,
    int gx, int Mlim, int MS, int K, int relu, int permrow)
{
    constexpr int MR     = BM / 32;
    constexpr int WRSPAN = BM / 2;
    constexpr int ABYTES = BM * 128;
    constexpr int PA     = ABYTES / 8192;
    constexpr int BUFB   = ABYTES + 16384;

    __shared__ __align__(16) char smem[2 * BUFB];

    const int tid  = threadIdx.x;
    const int lane = tid & 63;
    const int wid  = tid >> 6;
    const int wrow = wid >> 2;
    const int wcol = wid & 3;

    const int wgid = xcd_swz(blockIdx.x, gridDim.x);
    const int row0 = (wgid / gx) * BM;
    const int col0 = (wgid % gx) * 128;

    const int lrow  = lane & 15;
    const int lhalf = lane >> 4;
    const int koff0 = ((lhalf) ^ (lrow & 7)) * 16;
    const int koff1 = ((4 + lhalf) ^ (lrow & 7)) * 16;

    const int srow = tid >> 3;
    const int slot = tid & 7;
    const int sg   = slot ^ (srow & 7);

    f32x4 acc[MR][2] = {};

    const __bf16* Wsel = W;
    int wc0 = col0;
    if (col0 >= wsplit) { Wsel = W2; wc0 = col0 - wsplit; }

    const __bf16* Abase = A + (size_t)(row0 + srow) * K + sg * 8;
    const __bf16* Wbase = Wsel + (size_t)(wc0 + srow) * K + sg * 8;

    auto stage = [&](char* buf, int kt) {
#pragma unroll
        for (int p = 0; p < PA; ++p)
            gload_lds16(Abase + (size_t)p * 64 * K + kt, buf + p * 8192 + tid * 16);
#pragma unroll
        for (int p = 0; p < 2; ++p)
            gload_lds16(Wbase + (size_t)p * 64 * K + kt,
                        buf + ABYTES + p * 8192 + tid * 16);
    };

    stage(smem, 0);
    const int nkt = K >> 6;
    int cur = 0;
    for (int kt = 0; kt < nkt; ++kt) {
        __syncthreads();
        if (kt + 1 < nkt) stage(smem + (cur ^ 1) * BUFB, (kt + 1) * 64);
        const char* aB = smem + cur * BUFB + (wrow * WRSPAN + lrow) * 128;
        const char* wB = smem + cur * BUFB + ABYTES + (wcol * 32 + lrow) * 128;
#pragma unroll
        for (int ks = 0; ks < 2; ++ks) {
            const int ko = ks ? koff1 : koff0;
            bf16x8 af[MR], bfr[2];
#pragma unroll
            for (int m = 0; m < MR; ++m) af[m]  = *(const bf16x8*)(aB + m * 2048 + ko);
#pragma unroll
            for (int n = 0; n < 2; ++n)  bfr[n] = *(const bf16x8*)(wB + n * 2048 + ko);
            if (SWAP) {
#pragma unroll
                for (int m = 0; m < MR; ++m)
#pragma unroll
                    for (int n = 0; n < 2; ++n)
                        acc[m][n] = __builtin_amdgcn_mfma_f32_16x16x32_bf16(
                            bfr[n], af[m], acc[m][n], 0, 0, 0);
            } else {
#pragma unroll
                for (int m = 0; m < MR; ++m)
#pragma unroll
                    for (int n = 0; n < 2; ++n)
                        acc[m][n] = __builtin_amdgcn_mfma_f32_16x16x32_bf16(
                            af[m], bfr[n], acc[m][n], 0, 0, 0);
            }
        }
        cur ^= 1;
    }

    if (SWAP) {
#pragma unroll
        for (int m = 0; m < MR; ++m) {
            const int r = row0 + wrow * WRSPAN + m * 16 + lrow;
#pragma unroll
            for (int n = 0; n < 2; ++n) {
                const int c0 = col0 + wcol * 32 + n * 16 + lhalf * 4;
                const float4 bv = *(const float4*)(bias + c0);
                float o0 = acc[m][n][0] + bv.x, o1 = acc[m][n][1] + bv.y;
                float o2 = acc[m][n][2] + bv.z, o3 = acc[m][n][3] + bv.w;
                if (relu) {
                    o0 = fmaxf(o0, 0.f); o1 = fmaxf(o1, 0.f);
                    o2 = fmaxf(o2, 0.f); o3 = fmaxf(o3, 0.f);
                }
                if (OUTBF16) {
                    union { __bf16 h4[4]; u16x4 u; } pk;
                    pk.h4[0] = (__bf16)o0; pk.h4[1] = (__bf16)o1;
                    pk.h4[2] = (__bf16)o2; pk.h4[3] = (__bf16)o3;
                    *(u16x4*)((__bf16*)Cout + (size_t)r * MS + c0) = pk.u;
                } else {
                    *(float4*)((float*)Cout + (size_t)r * MS + c0) =
                        make_float4(o0, o1, o2, o3);
                }
            }
        }
    } else {
        const int orow = row0 + wrow * WRSPAN + lhalf * 4;
        const int ocol = col0 + wcol * 32 + lrow;
        const int smask = (1 << log2S) - 1;
#pragma unroll
        for (int n = 0; n < 2; ++n) {
            const int c = ocol + n * 16;
            if (c >= m_vt0) {
                const int cv = c - m_vt0;
                const int hh = cv >> 6, dd = cv & 63;
                const float bv = (bias2 && c >= bsplit) ? bias2[c - bsplit] : bias[c];
#pragma unroll
                for (int m = 0; m < MR; ++m) {
                    const int rr = orow + m * 16;
                    const int bb = rr >> log2S, ss = rr & smask;
                    union { __bf16 h4[4]; u16x4 u; } pk;
#pragma unroll
                    for (int j = 0; j < 4; ++j)
                        pk.h4[j] = (__bf16)(acc[m][n][j] + bv);
                    *(u16x4*)(VTout + (((size_t)((bb * 8 + hh) * 64 + dd)) << log2S) + ss) = pk.u;
                }
            } else if (c < Mlim) {
                const float bv = (bias2 && c >= bsplit) ? bias2[c - bsplit] : bias[c];
#pragma unroll
                for (int m = 0; m < MR; ++m) {
#pragma unroll
                    for (int j = 0; j < 4; ++j) {
                        int rr = orow + m * 16 + j;
                        if (permrow) rr = ((rr & smask) * BATCH) + (rr >> log2S);
                        float v = acc[m][n][j] + bv;
                        if (relu) v = fmaxf(v, 0.f);
                        if (OUTBF16) ((__bf16*)Cout)[(size_t)rr * MS + c] = (__bf16)v;
                        else         ((float*)Cout)[(size_t)rr * MS + c] = v;
                    }
                }
            }
        }
    }
}

// ---------------------------------------------------------------------------
// Fused GEMM (M=512) + residual add + LayerNorm, built on the VALIDATED
// BK=64 / 8-slot-swizzle staging + koff fragment reads from gemm_mfma.
//   O[r,:] = LN(X[r,:] + bf16round(A[r,:].W^T + bias)) * lnw + lnb
// BM=32 rows, BN=512 (full row/block), 512 thr (8 waves x 64-col slices).
// grid = N/32. K % 64 == 0. LDS: 2x(64K W + 4K A) + 2.2K stats = 141 KB.
// ---------------------------------------------------------------------------
__global__ __launch_bounds__(512) void gemm_ln(
    const __bf16* __restrict__ A, const __bf16* __restrict__ W,
    const float* __restrict__ bias, const float* __restrict__ Xres,
    const float* __restrict__ lnw, const float* __restrict__ lnb,
    float* __restrict__ Of, __bf16* __restrict__ Oh, int K)
{
    constexpr int WB2  = 512 * 128;     // 65536
    constexpr int AB2  = 32 * 128;      // 4096
    constexpr int BUFB = WB2 + AB2;     // 69632
    __shared__ __align__(16) char smem[2 * BUFB + 2176];
    float* redS = (float*)(smem + 2 * BUFB);
    float* redQ = (float*)(smem + 2 * BUFB + 1024);

    const int tid   = threadIdx.x;
    const int lane  = tid & 63;
    const int w     = tid >> 6;
    const int lrow  = lane & 15;
    const int lhalf = lane >> 4;
    const int row0  = blockIdx.x * 32;

    const int srow = tid >> 3;   // 0..63
    const int slot = tid & 7;
    const int sg   = slot ^ (srow & 7);

    const int koff0 = ((lhalf) ^ (lrow & 7)) * 16;
    const int koff1 = ((4 + lhalf) ^ (lrow & 7)) * 16;

    f32x4 acc[2][4] = {};

    auto stage = [&](char* buf, int kt) {
#pragma unroll
        for (int p = 0; p < 8; ++p) {
            const int wr = p * 64 + srow;
            gload_lds16(W + (size_t)wr * K + kt + sg * 8, buf + p * 8192 + tid * 16);
        }
        if (tid < 256) {
            gload_lds16(A + (size_t)(row0 + srow) * K + kt + sg * 8,
                        buf + WB2 + tid * 16);
        }
    };

    stage(smem, 0);
    const int nkt = K >> 6;
    int cur = 0;
    for (int kt = 0; kt < nkt; ++kt) {
        __syncthreads();
        if (kt + 1 < nkt) stage(smem + (cur ^ 1) * BUFB, (kt + 1) * 64);
        const char* wB = smem + cur * BUFB;
        const char* aB = wB + WB2;
#pragma unroll
        for (int ks = 0; ks < 2; ++ks) {
            const int ko = ks ? koff1 : koff0;
            bf16x8 af[2], bfr[4];
#pragma unroll
            for (int m = 0; m < 2; ++m)
                af[m] = *(const bf16x8*)(aB + (m * 16 + lrow) * 128 + ko);
#pragma unroll
            for (int n = 0; n < 4; ++n)
                bfr[n] = *(const bf16x8*)(wB + (w * 64 + n * 16 + lrow) * 128 + ko);
#pragma unroll
            for (int m = 0; m < 2; ++m)
#pragma unroll
                for (int n = 0; n < 4; ++n)
                    acc[m][n] = __builtin_amdgcn_mfma_f32_16x16x32_bf16(
                        bfr[n], af[m], acc[m][n], 0, 0, 0);
        }
        cur ^= 1;
    }

    // ---- epilogue: bf16-round(GEMM+bias) [mimics unfused path] + residual,
    //      per-row stats, LN, dual store ----
    float vals[2][4][4];
    float s[2] = {0.f, 0.f}, q[2] = {0.f, 0.f};
#pragma unroll
    for (int m = 0; m < 2; ++m) {
        const int r = row0 + m * 16 + lrow;
#pragma unroll
        for (int n = 0; n < 4; ++n) {
            const int c0 = w * 64 + n * 16 + lhalf * 4;
            const float4 bv = *(const float4*)(bias + c0);
            const float4 xv = *(const float4*)(Xres + (size_t)r * 512 + c0);
            const float v0 = (float)(__bf16)(acc[m][n][0] + bv.x) + xv.x;
            const float v1 = (float)(__bf16)(acc[m][n][1] + bv.y) + xv.y;
            const float v2 = (float)(__bf16)(acc[m][n][2] + bv.z) + xv.z;
            const float v3 = (float)(__bf16)(acc[m][n][3] + bv.w) + xv.w;
            vals[m][n][0] = v0; vals[m][n][1] = v1;
            vals[m][n][2] = v2; vals[m][n][3] = v3;
            s[m] += v0 + v1 + v2 + v3;
            q[m] += v0 * v0 + v1 * v1 + v2 * v2 + v3 * v3;
        }
    }
#pragma unroll
    for (int m = 0; m < 2; ++m) {
        s[m] += __shfl_xor(s[m], 16, 64); s[m] += __shfl_xor(s[m], 32, 64);
        q[m] += __shfl_xor(q[m], 16, 64); q[m] += __shfl_xor(q[m], 32, 64);
    }
    __syncthreads();
    if (lhalf == 0) {
#pragma unroll
        for (int m = 0; m < 2; ++m) {
            redS[(m * 16 + lrow) * 8 + w] = s[m];
            redQ[(m * 16 + lrow) * 8 + w] = q[m];
        }
    }
    __syncthreads();
    float mu[2], rstd[2];
#pragma unroll
    for (int m = 0; m < 2; ++m) {
        const int rr = m * 16 + lrow;
        float ts = 0.f, tq = 0.f;
#pragma unroll
        for (int ww = 0; ww < 8; ++ww) {
            ts += redS[rr * 8 + ww];
            tq += redQ[rr * 8 + ww];
        }
        mu[m] = ts * (1.f / 512.f);
        rstd[m] = rsqrtf(tq * (1.f / 512.f) - mu[m] * mu[m] + EPS_LN);
    }
#pragma unroll
    for (int m = 0; m < 2; ++m) {
        const int r = row0 + m * 16 + lrow;
#pragma unroll
        for (int n = 0; n < 4; ++n) {
            const int c0 = w * 64 + n * 16 + lhalf * 4;
            const float4 wv = *(const float4*)(lnw + c0);
            const float4 bb = *(const float4*)(lnb + c0);
            const float o0 = (vals[m][n][0] - mu[m]) * rstd[m] * wv.x + bb.x;
            const float o1 = (vals[m][n][1] - mu[m]) * rstd[m] * wv.y + bb.y;
            const float o2 = (vals[m][n][2] - mu[m]) * rstd[m] * wv.z + bb.z;
            const float o3 = (vals[m][n][3] - mu[m]) * rstd[m] * wv.w + bb.w;
            *(float4*)(Of + (size_t)r * 512 + c0) = make_float4(o0, o1, o2, o3);
            union { __bf16 h4[4]; u16x4 u; } pk;
            pk.h4[0] = (__bf16)o0; pk.h4[1] = (__bf16)o1;
            pk.h4[2] = (__bf16)o2; pk.h4[3] = (__bf16)o3;
            *(u16x4*)(Oh + (size_t)r * 512 + c0) = pk.u;
        }
    }
}

// ---------------------------------------------------------------------------
// MFMA flash attention, [b][s][*] layout, double-buffered K/V staging.
// ---------------------------------------------------------------------------
template <int CAUSAL>
__global__ __launch_bounds__(256) void attn_mfma(
    const __bf16* __restrict__ Qb, const __bf16* __restrict__ Kb,
    const __bf16* __restrict__ VT, __bf16* __restrict__ Op,
    int Sq, int Skv, int qstride, int kstride, int koff, float scale)
{
    __shared__ __align__(16) char smem[40960];
    const int tid = threadIdx.x;
    const int l   = tid & 63;
    const int w   = tid >> 6;
    char* Psm = smem + 32768 + w * 2048;

    const int qc = blockIdx.x;
    const int h  = blockIdx.y;
    const int b  = blockIdx.z;
    const int l15 = l & 15;
    const int g   = l >> 4;
    const int sw  = l15 & 7;

    const int sq = qc * 64 + w * 16 + l15;
    const __bf16* qrow = Qb + ((size_t)(b * Sq + sq)) * qstride + h * 64 + g * 8;
    const bf16x8 qf0 = *(const bf16x8*)(qrow);
    const bf16x8 qf1 = *(const bf16x8*)(qrow + 32);

    const int srow = tid >> 3;
    const int slot = tid & 7;

    auto stageKV = [&](char* buf, int kc) {
#pragma unroll
        for (int p = 0; p < 2; ++p) {
            const int r   = p * 32 + srow;
            const int sgo = (slot ^ (r & 7)) * 8;
            const __bf16* ksrc = Kb + ((size_t)(b * Skv + kc * 64 + r)) * kstride
                                    + koff + h * 64 + sgo;
            gload_lds16(ksrc, buf + (p * 256 + tid) * 16);
            const __bf16* vsrc = VT + ((size_t)((b * 8 + h) * 64 + r)) * Skv
                                    + kc * 64 + sgo;
            gload_lds16(vsrc, buf + 8192 + (p * 256 + tid) * 16);
        }
    };

    f32x4 acc[4] = {};
    float m_run = -1e30f, l_run = 0.f;

    const int nkc = CAUSAL ? (qc + 1) : (Skv >> 6);
    stageKV(smem, 0);
    int cur = 0;
    for (int kc = 0; kc < nkc; ++kc) {
        __syncthreads();
        if (kc + 1 < nkc) stageKV(smem + (cur ^ 1) * 16384, kc + 1);
        const char* Ksm = smem + cur * 16384;
        const char* Vsm = Ksm + 8192;

        f32x4 st[4];
#pragma unroll
        for (int f = 0; f < 4; ++f) {
            const char* kr = Ksm + (f * 16 + l15) * 128;
            bf16x8 ka0 = *(const bf16x8*)(kr + ((g ^ sw) * 16));
            bf16x8 ka1 = *(const bf16x8*)(kr + (((4 + g) ^ sw) * 16));
            f32x4 z = {};
            z = __builtin_amdgcn_mfma_f32_16x16x32_bf16(ka0, qf0, z, 0, 0, 0);
            st[f] = __builtin_amdgcn_mfma_f32_16x16x32_bf16(ka1, qf1, z, 0, 0, 0);
        }

        float rmax = -1e30f;
#pragma unroll
        for (int f = 0; f < 4; ++f)
#pragma unroll
            for (int j = 0; j < 4; ++j) {
                float v = st[f][j] * scale;
                if (CAUSAL) {
                    if (kc * 64 + f * 16 + g * 4 + j > sq) v = -1e30f;
                }
                st[f][j] = v;
                rmax = fmaxf(rmax, v);
            }
        rmax = fmaxf(rmax, __shfl_xor(rmax, 16, 64));
        rmax = fmaxf(rmax, __shfl_xor(rmax, 32, 64));
        const float mn = fmaxf(m_run, rmax);
        const float corr = __expf(m_run - mn);
        m_run = mn;
        float rsum = 0.f;
#pragma unroll
        for (int f = 0; f < 4; ++f)
#pragma unroll
            for (int j = 0; j < 4; ++j) {
                float p = __expf(st[f][j] - mn);
                st[f][j] = p;
                rsum += p;
            }
        rsum += __shfl_xor(rsum, 16, 64);
        rsum += __shfl_xor(rsum, 32, 64);
        l_run = l_run * corr + rsum;

#pragma unroll
        for (int j = 0; j < 4; ++j) {
            const float cj = __shfl(corr, g * 20 + j, 64);
            acc[0][j] *= cj; acc[1][j] *= cj; acc[2][j] *= cj; acc[3][j] *= cj;
        }

#pragma unroll
        for (int f = 0; f < 4; ++f)
#pragma unroll
            for (int j2 = 0; j2 < 2; ++j2) {
                union { __bf16 h2[2]; unsigned u; } cv;
                cv.h2[0] = (__bf16)st[f][2 * j2];
                cv.h2[1] = (__bf16)st[f][2 * j2 + 1];
                const int key0 = 16 * f + 4 * g + 2 * j2;
                const int byte = l15 * 128 + (((key0 >> 3) ^ sw) * 16) + (key0 & 7) * 2;
                *(unsigned*)(Psm + byte) = cv.u;
            }

#pragma unroll
        for (int ks = 0; ks < 2; ++ks) {
            const int so = ((4 * ks + g) ^ sw) * 16;
            bf16x8 pa = *(const bf16x8*)(Psm + l15 * 128 + so);
#pragma unroll
            for (int n = 0; n < 4; ++n) {
                bf16x8 vb = *(const bf16x8*)(Vsm + (n * 16 + l15) * 128 + so);
                acc[n] = __builtin_amdgcn_mfma_f32_16x16x32_bf16(pa, vb, acc[n], 0, 0, 0);
            }
        }
        cur ^= 1;
    }

    const float inv = 1.f / l_run;
#pragma unroll
    for (int j = 0; j < 4; ++j) {
        const float ij = __shfl(inv, g * 20 + j, 64);
        const int s = qc * 64 + w * 16 + g * 4 + j;
        __bf16* orow = Op + ((size_t)(b * Sq + s)) * D_MODEL + h * 64 + l15;
#pragma unroll
        for (int n = 0; n < 4; ++n)
            orow[n * 16] = (__bf16)(acc[n][j] * ij);
    }
}

// ---------------------------------------------------------------------------
// src [s][b][512] -> permuted [b][s][512], fp32 + bf16.  grid = 8192.
// ---------------------------------------------------------------------------
__global__ __launch_bounds__(256) void permute_src(
    const float* __restrict__ src, float* __restrict__ Of, __bf16* __restrict__ Oh)
{
    const int t = blockIdx.x;
    const int b = t >> 9, s = t & 511;
    const int tid = threadIdx.x;
    const float2 v = *(const float2*)(src + ((size_t)(s * BATCH + b)) * D_MODEL + tid * 2);
    *(float2*)(Of + (size_t)t * D_MODEL + tid * 2) = v;
    union { __bf16 h2[2]; u16x2 u; } cv;
    cv.h2[0] = (__bf16)v.x; cv.h2[1] = (__bf16)v.y;
    *(u16x2*)(Oh + (size_t)t * D_MODEL + tid * 2) = cv.u;
}

// ---------------------------------------------------------------------------
// Token embedding + posenc -> [b][s][512], fp32 + bf16. One block per row.
// ---------------------------------------------------------------------------
__global__ __launch_bounds__(256) void embed_pos(
    const int* __restrict__ tokens, const float* __restrict__ emb,
    float* __restrict__ Of, __bf16* __restrict__ Oh)
{
    const int t   = blockIdx.x;
    const int b   = t >> 7, s = t & 127;
    const int tid = threadIdx.x;
    const int tok = tokens[s * BATCH + b];
    const float C = 9.210340371976184f / 256.f;
    const int d = tid * 2;
    const int j = (d < 256) ? d : (d - 256);
    float a0 = (float)s * expf(-(float)j * C);
    float a1 = (float)s * expf(-(float)(j + 1) * C);
    float pe0 = (d < 256) ? sinf(a0) : cosf(a0);
    float pe1 = (d < 256) ? sinf(a1) : cosf(a1);
    const float2 e2 = *(const float2*)(emb + (size_t)tok * D_MODEL + d);
    float o0 = e2.x + pe0, o1 = e2.y + pe1;
    *(float2*)(Of + (size_t)t * D_MODEL + d) = make_float2(o0, o1);
    union { __bf16 h2[2]; u16x2 u; } cv;
    cv.h2[0] = (__bf16)o0; cv.h2[1] = (__bf16)o1;
    *(u16x2*)(Oh + (size_t)t * D_MODEL + d) = cv.u;
}

// ---------------------------------------------------------------------------
// Multi-segment fp32 -> bf16 (12 segments). Monotonic segment walk.
// ---------------------------------------------------------------------------
struct CvtSeg { const float* s; __bf16* d; int n8; };
struct CvtArgs { CvtSeg seg[12]; int tot8; };

__global__ __launch_bounds__(256) void cvt_multi(CvtArgs a)
{
    const int stride = gridDim.x * 256;
    int sgi = 0;
    int base = 0;
    for (int u = blockIdx.x * 256 + threadIdx.x; u < a.tot8; u += stride) {
        while (u - base >= a.seg[sgi].n8) { base += a.seg[sgi].n8; ++sgi; }
        const int v = u - base;
        const float4 f0 = ((const float4*)a.seg[sgi].s)[v * 2];
        const float4 f1 = ((const float4*)a.seg[sgi].s)[v * 2 + 1];
        union { __bf16 h[8]; u16x8 u; } c;
        c.h[0] = (__bf16)f0.x; c.h[1] = (__bf16)f0.y;
        c.h[2] = (__bf16)f0.z; c.h[3] = (__bf16)f0.w;
        c.h[4] = (__bf16)f1.x; c.h[5] = (__bf16)f1.y;
        c.h[6] = (__bf16)f1.z; c.h[7] = (__bf16)f1.w;
        ((u16x8*)a.seg[sgi].d)[v] = c.u;
    }
}

__global__ __launch_bounds__(256) void pad_outw(
    const float* __restrict__ w, __bf16* __restrict__ o)
{
    const int idx = blockIdx.x * 256 + threadIdx.x;
    const int r = idx >> 9;
    const int c = idx & 511;
    o[idx] = (__bf16)(r < 97 ? w[r * 512 + c] : 0.f);
}

// ---------------------------------------------------------------------------
// Host orchestration
// ---------------------------------------------------------------------------
extern "C" void kernel_launch(void* const* d_in, const int* in_sizes, int n_in,
                              void* d_out, int out_size, void* d_ws, size_t ws_size,
                              hipStream_t stream)
{
    const float* src     = (const float*)d_in[0];
    const int*   tokens  = (const int*)d_in[1];
    const float* tok_emb = (const float*)d_in[2];
    const float* enc_qkv_w = (const float*)d_in[3];
    const float* enc_qkv_b = (const float*)d_in[4];
    const float* enc_out_w = (const float*)d_in[5];
    const float* enc_out_b = (const float*)d_in[6];
    const float* enc_l1_w  = (const float*)d_in[7];
    const float* enc_l1_b  = (const float*)d_in[8];
    const float* enc_l2_w  = (const float*)d_in[9];
    const float* enc_l2_b  = (const float*)d_in[10];
    const float* enc_n1_w  = (const float*)d_in[11];
    const float* enc_n1_b  = (const float*)d_in[12];
    const float* enc_n2_w  = (const float*)d_in[13];
    const float* enc_n2_b  = (const float*)d_in[14];
    const float* dec_qkv_w = (const float*)d_in[15];
    const float* dec_qkv_b = (const float*)d_in[16];
    const float* dec_sout_w = (const float*)d_in[17];
    const float* dec_sout_b = (const float*)d_in[18];
    const float* dec_q_w   = (const float*)d_in[19];
    const float* dec_q_b   = (const float*)d_in[20];
    const float* dec_k_w   = (const float*)d_in[21];
    const float* dec_k_b   = (const float*)d_in[22];
    const float* dec_v_w   = (const float*)d_in[23];
    const float* dec_v_b   = (const float*)d_in[24];
    const float* dec_cout_w = (const float*)d_in[25];
    const float* dec_cout_b = (const float*)d_in[26];
    const float* dec_l1_w  = (const float*)d_in[27];
    const float* dec_l1_b  = (const float*)d_in[28];
    const float* dec_l2_w  = (const float*)d_in[29];
    const float* dec_l2_b  = (const float*)d_in[30];
    const float* dec_n1_w  = (const float*)d_in[31];
    const float* dec_n1_b  = (const float*)d_in[32];
    const float* dec_n2_w  = (const float*)d_in[33];
    const float* dec_n2_b  = (const float*)d_in[34];
    const float* dec_n3_w  = (const float*)d_in[35];
    const float* dec_n3_b  = (const float*)d_in[36];
    const float* out_w     = (const float*)d_in[37];
    const float* out_b     = (const float*)d_in[38];

    const int NE = 512 * BATCH;   // 8192 rows, [b][s]
    const int ND = 128 * BATCH;   // 2048 rows, [b][s]
    const float scale = 0.125f;
    const int BIG = 1 << 30;

    // -------- workspace layout (bytes) --------
    char* w8 = (char*)d_ws;
    float*  Ax_f = (float*) (w8 + 0);          // 16 MB enc residual fp32
    float*  T_f  = (float*) (w8 + 16777216);   //  4 MB dec residual fp32
    __bf16* Ax_h = (__bf16*)(w8 + 20971520);   //  8 MB enc bf16
    __bf16* T_h  = (__bf16*)(w8 + 29360128);   //  2 MB dec bf16
    __bf16* AO_h = (__bf16*)(w8 + 31457280);   //  8 MB attn out bf16
    __bf16* VT   = (__bf16*)(w8 + 48234496);   //  8 MB V-transpose
    __bf16* OWp  = (__bf16*)(w8 + 56623104);   //  0.13 MB padded out_w
    char*   Gb   = w8 + 56754176;              // 33.5 MB union
    __bf16* Gqk  = (__bf16*)Gb;                // qk bf16 [N][1024]
    __bf16* Gh   = (__bf16*)Gb;                // ffn hidden bf16 [N][2048]
    __bf16* Gq   = (__bf16*)Gb;                // cross q bf16 [2048][512]
    __bf16* Gk   = (__bf16*)(Gb + 2097152);    // cross k bf16 [8192][512]
    __bf16* WB   = (__bf16*)(w8 + 90308608);   // weights (88 MB upfront)

    const bool upfront = ws_size >= (size_t)178388992;

    auto gemmS = [&](const __bf16* Am, const __bf16* Wm, const float* bv,
                     void* C, int N, int M, int K, int relu) {
        const int nb128 = (M / 128) * (N / 128);
        const int gx = M / 128;
        if (nb128 >= 512) {
            gemm_mfma<128, 1, 1><<<gx * (N / 128), 512, 0, stream>>>(
                Am, Wm, nullptr, BIG, bv, nullptr, 0, C, nullptr, BIG, 0,
                gx, M, M, K, relu, 0);
        } else {
            gemm_mfma<64, 1, 1><<<gx * (N / 64), 512, 0, stream>>>(
                Am, Wm, nullptr, BIG, bv, nullptr, 0, C, nullptr, BIG, 0,
                gx, M, M, K, relu, 0);
        }
    };
    auto gemmN = [&](const __bf16* Am, const __bf16* Wm, const __bf16* W2m, int wsplit,
                     const float* bv, const float* bv2, int bsplit,
                     void* C, __bf16* VTp, int m_vt0, int log2S,
                     int N, int M, int MS, int K, bool outbf, int permrow) {
        const int gx = (M + 127) / 128;
        const int nb128 = gx * (N / 128);
        if (nb128 >= 512) {
            if (outbf) gemm_mfma<128, 1, 0><<<gx * (N / 128), 512, 0, stream>>>(
                Am, Wm, W2m, wsplit, bv, bv2, bsplit, C, VTp, m_vt0, log2S,
                gx, M, MS, K, 0, permrow);
            else       gemm_mfma<128, 0, 0><<<gx * (N / 128), 512, 0, stream>>>(
                Am, Wm, W2m, wsplit, bv, bv2, bsplit, C, VTp, m_vt0, log2S,
                gx, M, MS, K, 0, permrow);
        } else {
            if (outbf) gemm_mfma<64, 1, 0><<<gx * (N / 64), 512, 0, stream>>>(
                Am, Wm, W2m, wsplit, bv, bv2, bsplit, C, VTp, m_vt0, log2S,
                gx, M, MS, K, 0, permrow);
            else       gemm_mfma<64, 0, 0><<<gx * (N / 64), 512, 0, stream>>>(
                Am, Wm, W2m, wsplit, bv, bv2, bsplit, C, VTp, m_vt0, log2S,
                gx, M, MS, K, 0, permrow);
        }
    };
    auto gemmLN = [&](const __bf16* Am, const __bf16* Wm, const float* bv,
                      const float* Xr, const float* lw, const float* lb,
                      float* Of, __bf16* Oh, int N, int K) {
        gemm_ln<<<N / 32, 512, 0, stream>>>(Am, Wm, bv, Xr, lw, lb, Of, Oh, K);
    };
    auto cvt = [&](CvtArgs& a, int blocks) {
        int tot = 0;
        for (int i = 0; i < 12; ++i) tot += a.seg[i].n8;
        a.tot8 = tot;
        cvt_multi<<<blocks, 256, 0, stream>>>(a);
    };

    // ---- upfront: permute src, pad out_w, convert weights ----
    permute_src<<<NE, 256, 0, stream>>>(src, Ax_f, Ax_h);
    pad_outw<<<256, 256, 0, stream>>>(out_w, OWp);

    __bf16* WencQKV = WB;
    __bf16* WencOUT = WencQKV + 4718592;
    __bf16* WencL1  = WencOUT + 1572864;
    __bf16* WencL2  = WencL1 + 6291456;
    __bf16* WdecQKV = WencL2 + 6291456;
    __bf16* WdecSOUT = WdecQKV + 4718592;
    __bf16* WdecQ   = WdecSOUT + 1572864;
    __bf16* WdecK   = WdecQ + 1572864;
    __bf16* WdecV   = WdecK + 1572864;
    __bf16* WdecCOUT = WdecV + 1572864;
    __bf16* WdecL1  = WdecCOUT + 1572864;
    __bf16* WdecL2  = WdecL1 + 6291456;

    if (upfront) {
        CvtArgs a = {};
        a.seg[0]  = { enc_qkv_w,  WencQKV,  4718592 / 8 };
        a.seg[1]  = { enc_out_w,  WencOUT,  1572864 / 8 };
        a.seg[2]  = { enc_l1_w,   WencL1,   6291456 / 8 };
        a.seg[3]  = { enc_l2_w,   WencL2,   6291456 / 8 };
        a.seg[4]  = { dec_qkv_w,  WdecQKV,  4718592 / 8 };
        a.seg[5]  = { dec_sout_w, WdecSOUT, 1572864 / 8 };
        a.seg[6]  = { dec_q_w,    WdecQ,    1572864 / 8 };
        a.seg[7]  = { dec_k_w,    WdecK,    1572864 / 8 };
        a.seg[8]  = { dec_v_w,    WdecV,    1572864 / 8 };
        a.seg[9]  = { dec_cout_w, WdecCOUT, 1572864 / 8 };
        a.seg[10] = { dec_l1_w,   WdecL1,   6291456 / 8 };
        a.seg[11] = { dec_l2_w,   WdecL2,   6291456 / 8 };
        cvt(a, 4096);
    }

    // ---------------- Encoder ----------------
    for (int i = 0; i < 6; ++i) {
        __bf16 *wqkv, *wout, *wl1, *wl2;
        if (upfront) {
            wqkv = WencQKV + (size_t)i * 786432;
            wout = WencOUT + (size_t)i * 262144;
            wl1  = WencL1 + (size_t)i * 1048576;
            wl2  = WencL2 + (size_t)i * 1048576;
        } else {
            wqkv = WB; wout = WB + 786432; wl1 = WB + 1048576; wl2 = WB + 2097152;
            CvtArgs a = {};
            a.seg[0] = { enc_qkv_w + (size_t)i * 786432,  wqkv, 786432 / 8 };
            a.seg[1] = { enc_out_w + (size_t)i * 262144,  wout, 262144 / 8 };
            a.seg[2] = { enc_l1_w  + (size_t)i * 1048576, wl1, 1048576 / 8 };
            a.seg[3] = { enc_l2_w  + (size_t)i * 1048576, wl2, 1048576 / 8 };
            cvt(a, 1024);
        }

        gemmN(Ax_h, wqkv, nullptr, BIG, enc_qkv_b + (size_t)i * 1536, nullptr, 0,
              Gqk, VT, 1024, 9, NE, 1536, 1024, 512, true, 0);
        attn_mfma<0><<<dim3(8, 8, BATCH), 256, 0, stream>>>(
            Gqk, Gqk, VT, AO_h, 512, 512, 1024, 1024, 512, scale);
        gemmLN(AO_h, wout, enc_out_b + (size_t)i * 512, Ax_f,
               enc_n1_w + (size_t)i * 512, enc_n1_b + (size_t)i * 512,
               Ax_f, Ax_h, NE, 512);
        gemmS(Ax_h, wl1, enc_l1_b + (size_t)i * 2048, Gh, NE, 2048, 512, 1);
        gemmLN(Gh, wl2, enc_l2_b + (size_t)i * 512, Ax_f,
               enc_n2_w + (size_t)i * 512, enc_n2_b + (size_t)i * 512,
               Ax_f, Ax_h, NE, 2048);
    }

    // ---------------- Decoder ----------------
    embed_pos<<<ND, 256, 0, stream>>>(tokens, tok_emb, T_f, T_h);
    for (int i = 0; i < 6; ++i) {
        __bf16 *dqkv, *dsout, *dq, *dk, *dv, *dcout, *dl1, *dl2;
        if (upfront) {
            dqkv  = WdecQKV + (size_t)i * 786432;
            dsout = WdecSOUT + (size_t)i * 262144;
            dq    = WdecQ + (size_t)i * 262144;
            dk    = WdecK + (size_t)i * 262144;
            dv    = WdecV + (size_t)i * 262144;
            dcout = WdecCOUT + (size_t)i * 262144;
            dl1   = WdecL1 + (size_t)i * 1048576;
            dl2   = WdecL2 + (size_t)i * 1048576;
        } else {
            dqkv = WB; dsout = WB + 786432; dq = WB + 1048576; dk = WB + 1310720;
            dv = WB + 1572864; dcout = WB + 1835008; dl1 = WB + 2097152; dl2 = WB + 3145728;
            CvtArgs a = {};
            a.seg[0] = { dec_qkv_w  + (size_t)i * 786432,  dqkv,  786432 / 8 };
            a.seg[1] = { dec_sout_w + (size_t)i * 262144,  dsout, 262144 / 8 };
            a.seg[2] = { dec_q_w    + (size_t)i * 262144,  dq,    262144 / 8 };
            a.seg[3] = { dec_k_w    + (size_t)i * 262144,  dk,    262144 / 8 };
            a.seg[4] = { dec_v_w    + (size_t)i * 262144,  dv,    262144 / 8 };
            a.seg[5] = { dec_cout_w + (size_t)i * 262144,  dcout, 262144 / 8 };
            a.seg[6] = { dec_l1_w   + (size_t)i * 1048576, dl1,  1048576 / 8 };
            a.seg[7] = { dec_l2_w   + (size_t)i * 1048576, dl2,  1048576 / 8 };
            cvt(a, 1024);
        }

        // causal self-attn
        gemmN(T_h, dqkv, nullptr, BIG, dec_qkv_b + (size_t)i * 1536, nullptr, 0,
              Gqk, VT, 1024, 7, ND, 1536, 1024, 512, true, 0);
        attn_mfma<1><<<dim3(2, 8, BATCH), 256, 0, stream>>>(
            Gqk, Gqk, VT, AO_h, 128, 128, 1024, 1024, 512, scale);
        gemmLN(AO_h, dsout, dec_sout_b + (size_t)i * 512, T_f,
               dec_n1_w + (size_t)i * 512, dec_n1_b + (size_t)i * 512,
               T_f, T_h, ND, 512);
        // cross-attn
        gemmS(T_h, dq, dec_q_b + (size_t)i * 512, Gq, ND, 512, 512, 0);
        gemmN(Ax_h, dk, dv, 512, dec_k_b + (size_t)i * 512, dec_v_b + (size_t)i * 512, 512,
              Gk, VT, 512, 9, NE, 1024, 512, 512, true, 0);
        attn_mfma<0><<<dim3(2, 8, BATCH), 256, 0, stream>>>(
            Gq, Gk, VT, AO_h, 128, 512, 512, 512, 0, scale);
        gemmLN(AO_h, dcout, dec_cout_b + (size_t)i * 512, T_f,
               dec_n2_w + (size_t)i * 512, dec_n2_b + (size_t)i * 512,
               T_f, T_h, ND, 512);
        // FFN
        gemmS(T_h, dl1, dec_l1_b + (size_t)i * 2048, Gh, ND, 2048, 512, 1);
        gemmLN(Gh, dl2, dec_l2_b + (size_t)i * 512, T_f,
               dec_n3_w + (size_t)i * 512, dec_n3_b + (size_t)i * 512,
               T_f, T_h, ND, 2048);
    }

    // ---------------- Output projection (rows permuted back to [s][b]) ----
    gemmN(T_h, OWp, nullptr, BIG, out_b, nullptr, 0,
          (float*)d_out, nullptr, BIG, 7, ND, 97, 97, 512, false, 1);
}

// Round 10
// 1476.797 us; speedup vs baseline: 1.1480x; 1.1480x over previous
//
#include <hip/hip_runtime.h>
#include <hip/hip_bf16.h>
#include <cstddef>
#include <cstdint>

#define D_MODEL 512
#define BATCH 16
#define EPS_LN 1e-5f

typedef __bf16 bf16x8 __attribute__((ext_vector_type(8)));
typedef float f32x4 __attribute__((ext_vector_type(4)));
typedef unsigned short u16x8 __attribute__((ext_vector_type(8)));
typedef unsigned short u16x4 __attribute__((ext_vector_type(4)));
typedef unsigned short u16x2 __attribute__((ext_vector_type(2)));

__device__ __forceinline__ void gload_lds16(const void* g, void* l) {
    __builtin_amdgcn_global_load_lds(
        (const __attribute__((address_space(1))) void*)g,
        (__attribute__((address_space(3))) void*)l,
        16, 0, 0);
}

// Bijective XCD swizzle (m204): groups consecutive tiles per XCD.
__device__ __forceinline__ int xcd_swz(int wg, int nwg) {
    const int q = nwg >> 3, r = nwg & 7;
    const int x = wg & 7, p = wg >> 3;
    return (x < r ? x * (q + 1) : r * (q + 1) + (x - r) * q) + p;
}

// ---------------------------------------------------------------------------
// MFMA bf16 NT GEMM, activations [b][s][*] (row r = b*S + s).
// Tile BM x 128, BK=64, 512 threads (8 waves, 2x4), double-buffered 2-phase.
// 1D grid + XCD-aware bijective swizzle; gx = number of col-tiles.
// BM=128: 2 blk/CU (64KB LDS), wave tile 64x32 (4x2 frags).
// BM=64:  3 blk/CU (48KB LDS), wave tile 32x32 (2x2 frags) - skinny GEMMs.
// SWAP=1: swapped-operand epilogue -> vector stores, bf16, full tiles.
// SWAP=0: classic; col guard, VT side-output, dual bias, W split, permrow.
// ---------------------------------------------------------------------------
template <int BM, int OUTBF16, int SWAP>
__global__ __launch_bounds__(512) void gemm_mfma(
    const __bf16* __restrict__ A, const __bf16* __restrict__ W,
    const __bf16* __restrict__ W2, int wsplit,
    const float* __restrict__ bias, const float* __restrict__ bias2, int bsplit,
    void* __restrict__ Cout, __bf16* __restrict__ VTout, int m_vt0, int log2S,
    int gx, int Mlim, int MS, int K, int relu, int permrow)
{
    constexpr int MR     = BM / 32;
    constexpr int WRSPAN = BM / 2;
    constexpr int ABYTES = BM * 128;
    constexpr int PA     = ABYTES / 8192;
    constexpr int BUFB   = ABYTES + 16384;

    __shared__ __align__(16) char smem[2 * BUFB];

    const int tid  = threadIdx.x;
    const int lane = tid & 63;
    const int wid  = tid >> 6;
    const int wrow = wid >> 2;
    const int wcol = wid & 3;

    const int wgid = xcd_swz(blockIdx.x, gridDim.x);
    const int row0 = (wgid / gx) * BM;
    const int col0 = (wgid % gx) * 128;

    const int lrow  = lane & 15;
    const int lhalf = lane >> 4;
    const int koff0 = ((lhalf) ^ (lrow & 7)) * 16;
    const int koff1 = ((4 + lhalf) ^ (lrow & 7)) * 16;

    const int srow = tid >> 3;
    const int slot = tid & 7;
    const int sg   = slot ^ (srow & 7);

    f32x4 acc[MR][2] = {};

    const __bf16* Wsel = W;
    int wc0 = col0;
    if (col0 >= wsplit) { Wsel = W2; wc0 = col0 - wsplit; }

    const __bf16* Abase = A + (size_t)(row0 + srow) * K + sg * 8;
    const __bf16* Wbase = Wsel + (size_t)(wc0 + srow) * K + sg * 8;

    auto stage = [&](char* buf, int kt) {
#pragma unroll
        for (int p = 0; p < PA; ++p)
            gload_lds16(Abase + (size_t)p * 64 * K + kt, buf + p * 8192 + tid * 16);
#pragma unroll
        for (int p = 0; p < 2; ++p)
            gload_lds16(Wbase + (size_t)p * 64 * K + kt,
                        buf + ABYTES + p * 8192 + tid * 16);
    };

    stage(smem, 0);
    const int nkt = K >> 6;
    int cur = 0;
    for (int kt = 0; kt < nkt; ++kt) {
        __syncthreads();
        if (kt + 1 < nkt) stage(smem + (cur ^ 1) * BUFB, (kt + 1) * 64);
        const char* aB = smem + cur * BUFB + (wrow * WRSPAN + lrow) * 128;
        const char* wB = smem + cur * BUFB + ABYTES + (wcol * 32 + lrow) * 128;
#pragma unroll
        for (int ks = 0; ks < 2; ++ks) {
            const int ko = ks ? koff1 : koff0;
            bf16x8 af[MR], bfr[2];
#pragma unroll
            for (int m = 0; m < MR; ++m) af[m]  = *(const bf16x8*)(aB + m * 2048 + ko);
#pragma unroll
            for (int n = 0; n < 2; ++n)  bfr[n] = *(const bf16x8*)(wB + n * 2048 + ko);
            if (SWAP) {
#pragma unroll
                for (int m = 0; m < MR; ++m)
#pragma unroll
                    for (int n = 0; n < 2; ++n)
                        acc[m][n] = __builtin_amdgcn_mfma_f32_16x16x32_bf16(
                            bfr[n], af[m], acc[m][n], 0, 0, 0);
            } else {
#pragma unroll
                for (int m = 0; m < MR; ++m)
#pragma unroll
                    for (int n = 0; n < 2; ++n)
                        acc[m][n] = __builtin_amdgcn_mfma_f32_16x16x32_bf16(
                            af[m], bfr[n], acc[m][n], 0, 0, 0);
            }
        }
        cur ^= 1;
    }

    if (SWAP) {
#pragma unroll
        for (int m = 0; m < MR; ++m) {
            const int r = row0 + wrow * WRSPAN + m * 16 + lrow;
#pragma unroll
            for (int n = 0; n < 2; ++n) {
                const int c0 = col0 + wcol * 32 + n * 16 + lhalf * 4;
                const float4 bv = *(const float4*)(bias + c0);
                float o0 = acc[m][n][0] + bv.x, o1 = acc[m][n][1] + bv.y;
                float o2 = acc[m][n][2] + bv.z, o3 = acc[m][n][3] + bv.w;
                if (relu) {
                    o0 = fmaxf(o0, 0.f); o1 = fmaxf(o1, 0.f);
                    o2 = fmaxf(o2, 0.f); o3 = fmaxf(o3, 0.f);
                }
                if (OUTBF16) {
                    union { __bf16 h4[4]; u16x4 u; } pk;
                    pk.h4[0] = (__bf16)o0; pk.h4[1] = (__bf16)o1;
                    pk.h4[2] = (__bf16)o2; pk.h4[3] = (__bf16)o3;
                    *(u16x4*)((__bf16*)Cout + (size_t)r * MS + c0) = pk.u;
                } else {
                    *(float4*)((float*)Cout + (size_t)r * MS + c0) =
                        make_float4(o0, o1, o2, o3);
                }
            }
        }
    } else {
        const int orow = row0 + wrow * WRSPAN + lhalf * 4;
        const int ocol = col0 + wcol * 32 + lrow;
        const int smask = (1 << log2S) - 1;
#pragma unroll
        for (int n = 0; n < 2; ++n) {
            const int c = ocol + n * 16;
            if (c >= m_vt0) {
                const int cv = c - m_vt0;
                const int hh = cv >> 6, dd = cv & 63;
                const float bv = (bias2 && c >= bsplit) ? bias2[c - bsplit] : bias[c];
#pragma unroll
                for (int m = 0; m < MR; ++m) {
                    const int rr = orow + m * 16;
                    const int bb = rr >> log2S, ss = rr & smask;
                    union { __bf16 h4[4]; u16x4 u; } pk;
#pragma unroll
                    for (int j = 0; j < 4; ++j)
                        pk.h4[j] = (__bf16)(acc[m][n][j] + bv);
                    *(u16x4*)(VTout + (((size_t)((bb * 8 + hh) * 64 + dd)) << log2S) + ss) = pk.u;
                }
            } else if (c < Mlim) {
                const float bv = (bias2 && c >= bsplit) ? bias2[c - bsplit] : bias[c];
#pragma unroll
                for (int m = 0; m < MR; ++m) {
#pragma unroll
                    for (int j = 0; j < 4; ++j) {
                        int rr = orow + m * 16 + j;
                        if (permrow) rr = ((rr & smask) * BATCH) + (rr >> log2S);
                        float v = acc[m][n][j] + bv;
                        if (relu) v = fmaxf(v, 0.f);
                        if (OUTBF16) ((__bf16*)Cout)[(size_t)rr * MS + c] = (__bf16)v;
                        else         ((float*)Cout)[(size_t)rr * MS + c] = v;
                    }
                }
            }
        }
    }
}

// ---------------------------------------------------------------------------
// MFMA flash attention, [b][s][*] layout, double-buffered K/V staging.
// ---------------------------------------------------------------------------
template <int CAUSAL>
__global__ __launch_bounds__(256) void attn_mfma(
    const __bf16* __restrict__ Qb, const __bf16* __restrict__ Kb,
    const __bf16* __restrict__ VT, __bf16* __restrict__ Op,
    int Sq, int Skv, int qstride, int kstride, int koff, float scale)
{
    __shared__ __align__(16) char smem[40960];
    const int tid = threadIdx.x;
    const int l   = tid & 63;
    const int w   = tid >> 6;
    char* Psm = smem + 32768 + w * 2048;

    const int qc = blockIdx.x;
    const int h  = blockIdx.y;
    const int b  = blockIdx.z;
    const int l15 = l & 15;
    const int g   = l >> 4;
    const int sw  = l15 & 7;

    const int sq = qc * 64 + w * 16 + l15;
    const __bf16* qrow = Qb + ((size_t)(b * Sq + sq)) * qstride + h * 64 + g * 8;
    const bf16x8 qf0 = *(const bf16x8*)(qrow);
    const bf16x8 qf1 = *(const bf16x8*)(qrow + 32);

    const int srow = tid >> 3;
    const int slot = tid & 7;

    auto stageKV = [&](char* buf, int kc) {
#pragma unroll
        for (int p = 0; p < 2; ++p) {
            const int r   = p * 32 + srow;
            const int sgo = (slot ^ (r & 7)) * 8;
            const __bf16* ksrc = Kb + ((size_t)(b * Skv + kc * 64 + r)) * kstride
                                    + koff + h * 64 + sgo;
            gload_lds16(ksrc, buf + (p * 256 + tid) * 16);
            const __bf16* vsrc = VT + ((size_t)((b * 8 + h) * 64 + r)) * Skv
                                    + kc * 64 + sgo;
            gload_lds16(vsrc, buf + 8192 + (p * 256 + tid) * 16);
        }
    };

    f32x4 acc[4] = {};
    float m_run = -1e30f, l_run = 0.f;

    const int nkc = CAUSAL ? (qc + 1) : (Skv >> 6);
    stageKV(smem, 0);
    int cur = 0;
    for (int kc = 0; kc < nkc; ++kc) {
        __syncthreads();
        if (kc + 1 < nkc) stageKV(smem + (cur ^ 1) * 16384, kc + 1);
        const char* Ksm = smem + cur * 16384;
        const char* Vsm = Ksm + 8192;

        f32x4 st[4];
#pragma unroll
        for (int f = 0; f < 4; ++f) {
            const char* kr = Ksm + (f * 16 + l15) * 128;
            bf16x8 ka0 = *(const bf16x8*)(kr + ((g ^ sw) * 16));
            bf16x8 ka1 = *(const bf16x8*)(kr + (((4 + g) ^ sw) * 16));
            f32x4 z = {};
            z = __builtin_amdgcn_mfma_f32_16x16x32_bf16(ka0, qf0, z, 0, 0, 0);
            st[f] = __builtin_amdgcn_mfma_f32_16x16x32_bf16(ka1, qf1, z, 0, 0, 0);
        }

        float rmax = -1e30f;
#pragma unroll
        for (int f = 0; f < 4; ++f)
#pragma unroll
            for (int j = 0; j < 4; ++j) {
                float v = st[f][j] * scale;
                if (CAUSAL) {
                    if (kc * 64 + f * 16 + g * 4 + j > sq) v = -1e30f;
                }
                st[f][j] = v;
                rmax = fmaxf(rmax, v);
            }
        rmax = fmaxf(rmax, __shfl_xor(rmax, 16, 64));
        rmax = fmaxf(rmax, __shfl_xor(rmax, 32, 64));
        const float mn = fmaxf(m_run, rmax);
        const float corr = __expf(m_run - mn);
        m_run = mn;
        float rsum = 0.f;
#pragma unroll
        for (int f = 0; f < 4; ++f)
#pragma unroll
            for (int j = 0; j < 4; ++j) {
                float p = __expf(st[f][j] - mn);
                st[f][j] = p;
                rsum += p;
            }
        rsum += __shfl_xor(rsum, 16, 64);
        rsum += __shfl_xor(rsum, 32, 64);
        l_run = l_run * corr + rsum;

#pragma unroll
        for (int j = 0; j < 4; ++j) {
            const float cj = __shfl(corr, g * 20 + j, 64);
            acc[0][j] *= cj; acc[1][j] *= cj; acc[2][j] *= cj; acc[3][j] *= cj;
        }

#pragma unroll
        for (int f = 0; f < 4; ++f)
#pragma unroll
            for (int j2 = 0; j2 < 2; ++j2) {
                union { __bf16 h2[2]; unsigned u; } cv;
                cv.h2[0] = (__bf16)st[f][2 * j2];
                cv.h2[1] = (__bf16)st[f][2 * j2 + 1];
                const int key0 = 16 * f + 4 * g + 2 * j2;
                const int byte = l15 * 128 + (((key0 >> 3) ^ sw) * 16) + (key0 & 7) * 2;
                *(unsigned*)(Psm + byte) = cv.u;
            }

#pragma unroll
        for (int ks = 0; ks < 2; ++ks) {
            const int so = ((4 * ks + g) ^ sw) * 16;
            bf16x8 pa = *(const bf16x8*)(Psm + l15 * 128 + so);
#pragma unroll
            for (int n = 0; n < 4; ++n) {
                bf16x8 vb = *(const bf16x8*)(Vsm + (n * 16 + l15) * 128 + so);
                acc[n] = __builtin_amdgcn_mfma_f32_16x16x32_bf16(pa, vb, acc[n], 0, 0, 0);
            }
        }
        cur ^= 1;
    }

    const float inv = 1.f / l_run;
#pragma unroll
    for (int j = 0; j < 4; ++j) {
        const float ij = __shfl(inv, g * 20 + j, 64);
        const int s = qc * 64 + w * 16 + g * 4 + j;
        __bf16* orow = Op + ((size_t)(b * Sq + s)) * D_MODEL + h * 64 + l15;
#pragma unroll
        for (int n = 0; n < 4; ++n)
            orow[n * 16] = (__bf16)(acc[n][j] * ij);
    }
}

// ---------------------------------------------------------------------------
// Residual add + LayerNorm: X fp32 + Y bf16 -> fp32 + bf16. One block/row.
// ---------------------------------------------------------------------------
__global__ __launch_bounds__(256) void add_ln(
    const float* __restrict__ X, const __bf16* __restrict__ Y,
    const float* __restrict__ w, const float* __restrict__ bias,
    float* __restrict__ Of, __bf16* __restrict__ Oh)
{
    const int t   = blockIdx.x;
    const int tid = threadIdx.x;
    const float2 x2 = *(const float2*)(X + (size_t)t * D_MODEL + tid * 2);
    const u16x2 yv = *(const u16x2*)(Y + (size_t)t * D_MODEL + tid * 2);
    union { u16x2 u; __bf16 h2[2]; } yc; yc.u = yv;
    float v0 = x2.x + (float)yc.h2[0], v1 = x2.y + (float)yc.h2[1];
    float sum = v0 + v1;
    float sq  = v0 * v0 + v1 * v1;
#pragma unroll
    for (int off = 32; off; off >>= 1) {
        sum += __shfl_xor(sum, off);
        sq  += __shfl_xor(sq, off);
    }
    __shared__ float ssum[4], ssq[4];
    const int wid = tid >> 6;
    if ((tid & 63) == 0) { ssum[wid] = sum; ssq[wid] = sq; }
    __syncthreads();
    sum = ssum[0] + ssum[1] + ssum[2] + ssum[3];
    sq  = ssq[0] + ssq[1] + ssq[2] + ssq[3];

    const float mu  = sum * (1.f / D_MODEL);
    const float var = sq * (1.f / D_MODEL) - mu * mu;
    const float rs  = rsqrtf(var + EPS_LN);
    const float2 w2 = *(const float2*)(w + tid * 2);
    const float2 b2 = *(const float2*)(bias + tid * 2);
    float o0 = (v0 - mu) * rs * w2.x + b2.x;
    float o1 = (v1 - mu) * rs * w2.y + b2.y;
    *(float2*)(Of + (size_t)t * D_MODEL + tid * 2) = make_float2(o0, o1);
    union { __bf16 h2[2]; u16x2 u; } cv;
    cv.h2[0] = (__bf16)o0; cv.h2[1] = (__bf16)o1;
    *(u16x2*)(Oh + (size_t)t * D_MODEL + tid * 2) = cv.u;
}

// ---------------------------------------------------------------------------
// src [s][b][512] -> permuted [b][s][512], fp32 + bf16.  grid = 8192.
// ---------------------------------------------------------------------------
__global__ __launch_bounds__(256) void permute_src(
    const float* __restrict__ src, float* __restrict__ Of, __bf16* __restrict__ Oh)
{
    const int t = blockIdx.x;
    const int b = t >> 9, s = t & 511;
    const int tid = threadIdx.x;
    const float2 v = *(const float2*)(src + ((size_t)(s * BATCH + b)) * D_MODEL + tid * 2);
    *(float2*)(Of + (size_t)t * D_MODEL + tid * 2) = v;
    union { __bf16 h2[2]; u16x2 u; } cv;
    cv.h2[0] = (__bf16)v.x; cv.h2[1] = (__bf16)v.y;
    *(u16x2*)(Oh + (size_t)t * D_MODEL + tid * 2) = cv.u;
}

// ---------------------------------------------------------------------------
// Token embedding + posenc -> [b][s][512], fp32 + bf16. One block per row.
// ---------------------------------------------------------------------------
__global__ __launch_bounds__(256) void embed_pos(
    const int* __restrict__ tokens, const float* __restrict__ emb,
    float* __restrict__ Of, __bf16* __restrict__ Oh)
{
    const int t   = blockIdx.x;
    const int b   = t >> 7, s = t & 127;
    const int tid = threadIdx.x;
    const int tok = tokens[s * BATCH + b];
    const float C = 9.210340371976184f / 256.f;
    const int d = tid * 2;
    const int j = (d < 256) ? d : (d - 256);
    float a0 = (float)s * expf(-(float)j * C);
    float a1 = (float)s * expf(-(float)(j + 1) * C);
    float pe0 = (d < 256) ? sinf(a0) : cosf(a0);
    float pe1 = (d < 256) ? sinf(a1) : cosf(a1);
    const float2 e2 = *(const float2*)(emb + (size_t)tok * D_MODEL + d);
    float o0 = e2.x + pe0, o1 = e2.y + pe1;
    *(float2*)(Of + (size_t)t * D_MODEL + d) = make_float2(o0, o1);
    union { __bf16 h2[2]; u16x2 u; } cv;
    cv.h2[0] = (__bf16)o0; cv.h2[1] = (__bf16)o1;
    *(u16x2*)(Oh + (size_t)t * D_MODEL + d) = cv.u;
}

// ---------------------------------------------------------------------------
// Multi-segment fp32 -> bf16 (12 segments). Monotonic segment walk.
// ---------------------------------------------------------------------------
struct CvtSeg { const float* s; __bf16* d; int n8; };
struct CvtArgs { CvtSeg seg[12]; int tot8; };

__global__ __launch_bounds__(256) void cvt_multi(CvtArgs a)
{
    const int stride = gridDim.x * 256;
    int sgi = 0;
    int base = 0;
    for (int u = blockIdx.x * 256 + threadIdx.x; u < a.tot8; u += stride) {
        while (u - base >= a.seg[sgi].n8) { base += a.seg[sgi].n8; ++sgi; }
        const int v = u - base;
        const float4 f0 = ((const float4*)a.seg[sgi].s)[v * 2];
        const float4 f1 = ((const float4*)a.seg[sgi].s)[v * 2 + 1];
        union { __bf16 h[8]; u16x8 u; } c;
        c.h[0] = (__bf16)f0.x; c.h[1] = (__bf16)f0.y;
        c.h[2] = (__bf16)f0.z; c.h[3] = (__bf16)f0.w;
        c.h[4] = (__bf16)f1.x; c.h[5] = (__bf16)f1.y;
        c.h[6] = (__bf16)f1.z; c.h[7] = (__bf16)f1.w;
        ((u16x8*)a.seg[sgi].d)[v] = c.u;
    }
}

__global__ __launch_bounds__(256) void pad_outw(
    const float* __restrict__ w, __bf16* __restrict__ o)
{
    const int idx = blockIdx.x * 256 + threadIdx.x;
    const int r = idx >> 9;
    const int c = idx & 511;
    o[idx] = (__bf16)(r < 97 ? w[r * 512 + c] : 0.f);
}

// ---------------------------------------------------------------------------
// Host orchestration
// ---------------------------------------------------------------------------
extern "C" void kernel_launch(void* const* d_in, const int* in_sizes, int n_in,
                              void* d_out, int out_size, void* d_ws, size_t ws_size,
                              hipStream_t stream)
{
    const float* src     = (const float*)d_in[0];
    const int*   tokens  = (const int*)d_in[1];
    const float* tok_emb = (const float*)d_in[2];
    const float* enc_qkv_w = (const float*)d_in[3];
    const float* enc_qkv_b = (const float*)d_in[4];
    const float* enc_out_w = (const float*)d_in[5];
    const float* enc_out_b = (const float*)d_in[6];
    const float* enc_l1_w  = (const float*)d_in[7];
    const float* enc_l1_b  = (const float*)d_in[8];
    const float* enc_l2_w  = (const float*)d_in[9];
    const float* enc_l2_b  = (const float*)d_in[10];
    const float* enc_n1_w  = (const float*)d_in[11];
    const float* enc_n1_b  = (const float*)d_in[12];
    const float* enc_n2_w  = (const float*)d_in[13];
    const float* enc_n2_b  = (const float*)d_in[14];
    const float* dec_qkv_w = (const float*)d_in[15];
    const float* dec_qkv_b = (const float*)d_in[16];
    const float* dec_sout_w = (const float*)d_in[17];
    const float* dec_sout_b = (const float*)d_in[18];
    const float* dec_q_w   = (const float*)d_in[19];
    const float* dec_q_b   = (const float*)d_in[20];
    const float* dec_k_w   = (const float*)d_in[21];
    const float* dec_k_b   = (const float*)d_in[22];
    const float* dec_v_w   = (const float*)d_in[23];
    const float* dec_v_b   = (const float*)d_in[24];
    const float* dec_cout_w = (const float*)d_in[25];
    const float* dec_cout_b = (const float*)d_in[26];
    const float* dec_l1_w  = (const float*)d_in[27];
    const float* dec_l1_b  = (const float*)d_in[28];
    const float* dec_l2_w  = (const float*)d_in[29];
    const float* dec_l2_b  = (const float*)d_in[30];
    const float* dec_n1_w  = (const float*)d_in[31];
    const float* dec_n1_b  = (const float*)d_in[32];
    const float* dec_n2_w  = (const float*)d_in[33];
    const float* dec_n2_b  = (const float*)d_in[34];
    const float* dec_n3_w  = (const float*)d_in[35];
    const float* dec_n3_b  = (const float*)d_in[36];
    const float* out_w     = (const float*)d_in[37];
    const float* out_b     = (const float*)d_in[38];

    const int NE = 512 * BATCH;   // 8192 rows, [b][s]
    const int ND = 128 * BATCH;   // 2048 rows, [b][s]
    const float scale = 0.125f;
    const int BIG = 1 << 30;

    // -------- workspace layout (bytes) --------
    char* w8 = (char*)d_ws;
    float*  Ax_f = (float*) (w8 + 0);          // 16 MB enc residual fp32
    float*  T_f  = (float*) (w8 + 16777216);   //  4 MB dec residual fp32
    __bf16* Ax_h = (__bf16*)(w8 + 20971520);   //  8 MB enc bf16
    __bf16* T_h  = (__bf16*)(w8 + 29360128);   //  2 MB dec bf16
    __bf16* AO_h = (__bf16*)(w8 + 31457280);   //  8 MB attn out bf16
    __bf16* Y_h  = (__bf16*)(w8 + 39845888);   //  8 MB residual-Y bf16
    __bf16* VT   = (__bf16*)(w8 + 48234496);   //  8 MB V-transpose
    __bf16* OWp  = (__bf16*)(w8 + 56623104);   //  0.13 MB padded out_w
    char*   Gb   = w8 + 56754176;              // 33.5 MB union
    __bf16* Gqk  = (__bf16*)Gb;                // qk bf16 [N][1024]
    __bf16* Gh   = (__bf16*)Gb;                // ffn hidden bf16 [N][2048]
    __bf16* Gq   = (__bf16*)Gb;                // cross q bf16 [2048][512]
    __bf16* Gk   = (__bf16*)(Gb + 2097152);    // cross k bf16 [8192][512]
    __bf16* WB   = (__bf16*)(w8 + 90308608);   // weights (88 MB upfront)

    const bool upfront = ws_size >= (size_t)178388992;

    auto gemmS = [&](const __bf16* Am, const __bf16* Wm, const float* bv,
                     void* C, int N, int M, int K, int relu) {
        const int nb128 = (M / 128) * (N / 128);
        const int gx = M / 128;
        if (nb128 >= 512) {
            gemm_mfma<128, 1, 1><<<gx * (N / 128), 512, 0, stream>>>(
                Am, Wm, nullptr, BIG, bv, nullptr, 0, C, nullptr, BIG, 0,
                gx, M, M, K, relu, 0);
        } else {
            gemm_mfma<64, 1, 1><<<gx * (N / 64), 512, 0, stream>>>(
                Am, Wm, nullptr, BIG, bv, nullptr, 0, C, nullptr, BIG, 0,
                gx, M, M, K, relu, 0);
        }
    };
    auto gemmN = [&](const __bf16* Am, const __bf16* Wm, const __bf16* W2m, int wsplit,
                     const float* bv, const float* bv2, int bsplit,
                     void* C, __bf16* VTp, int m_vt0, int log2S,
                     int N, int M, int MS, int K, bool outbf, int permrow) {
        const int gx = (M + 127) / 128;
        const int nb128 = gx * (N / 128);
        if (nb128 >= 512) {
            if (outbf) gemm_mfma<128, 1, 0><<<gx * (N / 128), 512, 0, stream>>>(
                Am, Wm, W2m, wsplit, bv, bv2, bsplit, C, VTp, m_vt0, log2S,
                gx, M, MS, K, 0, permrow);
            else       gemm_mfma<128, 0, 0><<<gx * (N / 128), 512, 0, stream>>>(
                Am, Wm, W2m, wsplit, bv, bv2, bsplit, C, VTp, m_vt0, log2S,
                gx, M, MS, K, 0, permrow);
        } else {
            if (outbf) gemm_mfma<64, 1, 0><<<gx * (N / 64), 512, 0, stream>>>(
                Am, Wm, W2m, wsplit, bv, bv2, bsplit, C, VTp, m_vt0, log2S,
                gx, M, MS, K, 0, permrow);
            else       gemm_mfma<64, 0, 0><<<gx * (N / 64), 512, 0, stream>>>(
                Am, Wm, W2m, wsplit, bv, bv2, bsplit, C, VTp, m_vt0, log2S,
                gx, M, MS, K, 0, permrow);
        }
    };
    auto cvt = [&](CvtArgs& a, int blocks) {
        int tot = 0;
        for (int i = 0; i < 12; ++i) tot += a.seg[i].n8;
        a.tot8 = tot;
        cvt_multi<<<blocks, 256, 0, stream>>>(a);
    };

    // ---- upfront: permute src, pad out_w, convert weights ----
    permute_src<<<NE, 256, 0, stream>>>(src, Ax_f, Ax_h);
    pad_outw<<<256, 256, 0, stream>>>(out_w, OWp);

    __bf16* WencQKV = WB;
    __bf16* WencOUT = WencQKV + 4718592;
    __bf16* WencL1  = WencOUT + 1572864;
    __bf16* WencL2  = WencL1 + 6291456;
    __bf16* WdecQKV = WencL2 + 6291456;
    __bf16* WdecSOUT = WdecQKV + 4718592;
    __bf16* WdecQ   = WdecSOUT + 1572864;
    __bf16* WdecK   = WdecQ + 1572864;
    __bf16* WdecV   = WdecK + 1572864;
    __bf16* WdecCOUT = WdecV + 1572864;
    __bf16* WdecL1  = WdecCOUT + 1572864;
    __bf16* WdecL2  = WdecL1 + 6291456;

    if (upfront) {
        CvtArgs a = {};
        a.seg[0]  = { enc_qkv_w,  WencQKV,  4718592 / 8 };
        a.seg[1]  = { enc_out_w,  WencOUT,  1572864 / 8 };
        a.seg[2]  = { enc_l1_w,   WencL1,   6291456 / 8 };
        a.seg[3]  = { enc_l2_w,   WencL2,   6291456 / 8 };
        a.seg[4]  = { dec_qkv_w,  WdecQKV,  4718592 / 8 };
        a.seg[5]  = { dec_sout_w, WdecSOUT, 1572864 / 8 };
        a.seg[6]  = { dec_q_w,    WdecQ,    1572864 / 8 };
        a.seg[7]  = { dec_k_w,    WdecK,    1572864 / 8 };
        a.seg[8]  = { dec_v_w,    WdecV,    1572864 / 8 };
        a.seg[9]  = { dec_cout_w, WdecCOUT, 1572864 / 8 };
        a.seg[10] = { dec_l1_w,   WdecL1,   6291456 / 8 };
        a.seg[11] = { dec_l2_w,   WdecL2,   6291456 / 8 };
        cvt(a, 4096);
    }

    // ---------------- Encoder ----------------
    for (int i = 0; i < 6; ++i) {
        __bf16 *wqkv, *wout, *wl1, *wl2;
        if (upfront) {
            wqkv = WencQKV + (size_t)i * 786432;
            wout = WencOUT + (size_t)i * 262144;
            wl1  = WencL1 + (size_t)i * 1048576;
            wl2  = WencL2 + (size_t)i * 1048576;
        } else {
            wqkv = WB; wout = WB + 786432; wl1 = WB + 1048576; wl2 = WB + 2097152;
            CvtArgs a = {};
            a.seg[0] = { enc_qkv_w + (size_t)i * 786432,  wqkv, 786432 / 8 };
            a.seg[1] = { enc_out_w + (size_t)i * 262144,  wout, 262144 / 8 };
            a.seg[2] = { enc_l1_w  + (size_t)i * 1048576, wl1, 1048576 / 8 };
            a.seg[3] = { enc_l2_w  + (size_t)i * 1048576, wl2, 1048576 / 8 };
            cvt(a, 1024);
        }

        gemmN(Ax_h, wqkv, nullptr, BIG, enc_qkv_b + (size_t)i * 1536, nullptr, 0,
              Gqk, VT, 1024, 9, NE, 1536, 1024, 512, true, 0);
        attn_mfma<0><<<dim3(8, 8, BATCH), 256, 0, stream>>>(
            Gqk, Gqk, VT, AO_h, 512, 512, 1024, 1024, 512, scale);
        gemmS(AO_h, wout, enc_out_b + (size_t)i * 512, Y_h, NE, 512, 512, 0);
        add_ln<<<NE, 256, 0, stream>>>(Ax_f, Y_h,
                                       enc_n1_w + (size_t)i * 512, enc_n1_b + (size_t)i * 512,
                                       Ax_f, Ax_h);
        gemmS(Ax_h, wl1, enc_l1_b + (size_t)i * 2048, Gh, NE, 2048, 512, 1);
        gemmS(Gh, wl2, enc_l2_b + (size_t)i * 512, Y_h, NE, 512, 2048, 0);
        add_ln<<<NE, 256, 0, stream>>>(Ax_f, Y_h,
                                       enc_n2_w + (size_t)i * 512, enc_n2_b + (size_t)i * 512,
                                       Ax_f, Ax_h);
    }

    // ---------------- Decoder ----------------
    embed_pos<<<ND, 256, 0, stream>>>(tokens, tok_emb, T_f, T_h);
    for (int i = 0; i < 6; ++i) {
        __bf16 *dqkv, *dsout, *dq, *dk, *dv, *dcout, *dl1, *dl2;
        if (upfront) {
            dqkv  = WdecQKV + (size_t)i * 786432;
            dsout = WdecSOUT + (size_t)i * 262144;
            dq    = WdecQ + (size_t)i * 262144;
            dk    = WdecK + (size_t)i * 262144;
            dv    = WdecV + (size_t)i * 262144;
            dcout = WdecCOUT + (size_t)i * 262144;
            dl1   = WdecL1 + (size_t)i * 1048576;
            dl2   = WdecL2 + (size_t)i * 1048576;
        } else {
            dqkv = WB; dsout = WB + 786432; dq = WB + 1048576; dk = WB + 1310720;
            dv = WB + 1572864; dcout = WB + 1835008; dl1 = WB + 2097152; dl2 = WB + 3145728;
            CvtArgs a = {};
            a.seg[0] = { dec_qkv_w  + (size_t)i * 786432,  dqkv,  786432 / 8 };
            a.seg[1] = { dec_sout_w + (size_t)i * 262144,  dsout, 262144 / 8 };
            a.seg[2] = { dec_q_w    + (size_t)i * 262144,  dq,    262144 / 8 };
            a.seg[3] = { dec_k_w    + (size_t)i * 262144,  dk,    262144 / 8 };
            a.seg[4] = { dec_v_w    + (size_t)i * 262144,  dv,    262144 / 8 };
            a.seg[5] = { dec_cout_w + (size_t)i * 262144,  dcout, 262144 / 8 };
            a.seg[6] = { dec_l1_w   + (size_t)i * 1048576, dl1,  1048576 / 8 };
            a.seg[7] = { dec_l2_w   + (size_t)i * 1048576, dl2,  1048576 / 8 };
            cvt(a, 1024);
        }

        // causal self-attn
        gemmN(T_h, dqkv, nullptr, BIG, dec_qkv_b + (size_t)i * 1536, nullptr, 0,
              Gqk, VT, 1024, 7, ND, 1536, 1024, 512, true, 0);
        attn_mfma<1><<<dim3(2, 8, BATCH), 256, 0, stream>>>(
            Gqk, Gqk, VT, AO_h, 128, 128, 1024, 1024, 512, scale);
        gemmS(AO_h, dsout, dec_sout_b + (size_t)i * 512, Y_h, ND, 512, 512, 0);
        add_ln<<<ND, 256, 0, stream>>>(T_f, Y_h,
                                       dec_n1_w + (size_t)i * 512, dec_n1_b + (size_t)i * 512,
                                       T_f, T_h);
        // cross-attn
        gemmS(T_h, dq, dec_q_b + (size_t)i * 512, Gq, ND, 512, 512, 0);
        gemmN(Ax_h, dk, dv, 512, dec_k_b + (size_t)i * 512, dec_v_b + (size_t)i * 512, 512,
              Gk, VT, 512, 9, NE, 1024, 512, 512, true, 0);
        attn_mfma<0><<<dim3(2, 8, BATCH), 256, 0, stream>>>(
            Gq, Gk, VT, AO_h, 128, 512, 512, 512, 0, scale);
        gemmS(AO_h, dcout, dec_cout_b + (size_t)i * 512, Y_h, ND, 512, 512, 0);
        add_ln<<<ND, 256, 0, stream>>>(T_f, Y_h,
                                       dec_n2_w + (size_t)i * 512, dec_n2_b + (size_t)i * 512,
                                       T_f, T_h);
        // FFN
        gemmS(T_h, dl1, dec_l1_b + (size_t)i * 2048, Gh, ND, 2048, 512, 1);
        gemmS(Gh, dl2, dec_l2_b + (size_t)i * 512, Y_h, ND, 512, 2048, 0);
        add_ln<<<ND, 256, 0, stream>>>(T_f, Y_h,
                                       dec_n3_w + (size_t)i * 512, dec_n3_b + (size_t)i * 512,
                                       T_f, T_h);
    }

    // ---------------- Output projection (rows permuted back to [s][b]) ----
    gemmN(T_h, OWp, nullptr, BIG, out_b, nullptr, 0,
          (float*)d_out, nullptr, BIG, 7, ND, 97, 97, 512, false, 1);
}

// Round 11
// 1389.393 us; speedup vs baseline: 1.2202x; 1.0629x over previous
//
#include <hip/hip_runtime.h>
#include <hip/hip_bf16.h>
#include <cstddef>
#include <cstdint>

#define D_MODEL 512
#define BATCH 16
#define EPS_LN 1e-5f

typedef __bf16 bf16x8 __attribute__((ext_vector_type(8)));
typedef float f32x4 __attribute__((ext_vector_type(4)));
typedef unsigned short u16x8 __attribute__((ext_vector_type(8)));
typedef unsigned short u16x4 __attribute__((ext_vector_type(4)));
typedef unsigned short u16x2 __attribute__((ext_vector_type(2)));

__device__ __forceinline__ void gload_lds16(const void* g, void* l) {
    __builtin_amdgcn_global_load_lds(
        (const __attribute__((address_space(1))) void*)g,
        (__attribute__((address_space(3))) void*)l,
        16, 0, 0);
}

// Bijective XCD swizzle (m204): groups consecutive tiles per XCD.
__device__ __forceinline__ int xcd_swz(int wg, int nwg) {
    const int q = nwg >> 3, r = nwg & 7;
    const int x = wg & 7, p = wg >> 3;
    return (x < r ? x * (q + 1) : r * (q + 1) + (x - r) * q) + p;
}

// ---------------------------------------------------------------------------
// MFMA bf16 NT GEMM, activations [b][s][*] (row r = b*S + s).
// Tile BM x 128, BK=64, 512 threads (8 waves, 2x4), double-buffered 2-phase.
// 1D grid + XCD-aware bijective swizzle; gx = number of col-tiles.
// SWAP=1: swapped-operand epilogue -> vector stores, bf16, full tiles.
// SWAP=0: classic; col guard, VT side-output, dual bias, W split, permrow.
// ---------------------------------------------------------------------------
template <int BM, int OUTBF16, int SWAP>
__global__ __launch_bounds__(512) void gemm_mfma(
    const __bf16* __restrict__ A, const __bf16* __restrict__ W,
    const __bf16* __restrict__ W2, int wsplit,
    const float* __restrict__ bias, const float* __restrict__ bias2, int bsplit,
    void* __restrict__ Cout, __bf16* __restrict__ VTout, int m_vt0, int log2S,
    int gx, int Mlim, int MS, int K, int relu, int permrow)
{
    constexpr int MR     = BM / 32;
    constexpr int WRSPAN = BM / 2;
    constexpr int ABYTES = BM * 128;
    constexpr int PA     = ABYTES / 8192;
    constexpr int BUFB   = ABYTES + 16384;

    __shared__ __align__(16) char smem[2 * BUFB];

    const int tid  = threadIdx.x;
    const int lane = tid & 63;
    const int wid  = tid >> 6;
    const int wrow = wid >> 2;
    const int wcol = wid & 3;

    const int wgid = xcd_swz(blockIdx.x, gridDim.x);
    const int row0 = (wgid / gx) * BM;
    const int col0 = (wgid % gx) * 128;

    const int lrow  = lane & 15;
    const int lhalf = lane >> 4;
    const int koff0 = ((lhalf) ^ (lrow & 7)) * 16;
    const int koff1 = ((4 + lhalf) ^ (lrow & 7)) * 16;

    const int srow = tid >> 3;
    const int slot = tid & 7;
    const int sg   = slot ^ (srow & 7);

    f32x4 acc[MR][2] = {};

    const __bf16* Wsel = W;
    int wc0 = col0;
    if (col0 >= wsplit) { Wsel = W2; wc0 = col0 - wsplit; }

    const __bf16* Abase = A + (size_t)(row0 + srow) * K + sg * 8;
    const __bf16* Wbase = Wsel + (size_t)(wc0 + srow) * K + sg * 8;

    auto stage = [&](char* buf, int kt) {
#pragma unroll
        for (int p = 0; p < PA; ++p)
            gload_lds16(Abase + (size_t)p * 64 * K + kt, buf + p * 8192 + tid * 16);
#pragma unroll
        for (int p = 0; p < 2; ++p)
            gload_lds16(Wbase + (size_t)p * 64 * K + kt,
                        buf + ABYTES + p * 8192 + tid * 16);
    };

    stage(smem, 0);
    const int nkt = K >> 6;
    int cur = 0;
    for (int kt = 0; kt < nkt; ++kt) {
        __syncthreads();
        if (kt + 1 < nkt) stage(smem + (cur ^ 1) * BUFB, (kt + 1) * 64);
        const char* aB = smem + cur * BUFB + (wrow * WRSPAN + lrow) * 128;
        const char* wB = smem + cur * BUFB + ABYTES + (wcol * 32 + lrow) * 128;
#pragma unroll
        for (int ks = 0; ks < 2; ++ks) {
            const int ko = ks ? koff1 : koff0;
            bf16x8 af[MR], bfr[2];
#pragma unroll
            for (int m = 0; m < MR; ++m) af[m]  = *(const bf16x8*)(aB + m * 2048 + ko);
#pragma unroll
            for (int n = 0; n < 2; ++n)  bfr[n] = *(const bf16x8*)(wB + n * 2048 + ko);
            if (SWAP) {
#pragma unroll
                for (int m = 0; m < MR; ++m)
#pragma unroll
                    for (int n = 0; n < 2; ++n)
                        acc[m][n] = __builtin_amdgcn_mfma_f32_16x16x32_bf16(
                            bfr[n], af[m], acc[m][n], 0, 0, 0);
            } else {
#pragma unroll
                for (int m = 0; m < MR; ++m)
#pragma unroll
                    for (int n = 0; n < 2; ++n)
                        acc[m][n] = __builtin_amdgcn_mfma_f32_16x16x32_bf16(
                            af[m], bfr[n], acc[m][n], 0, 0, 0);
            }
        }
        cur ^= 1;
    }

    if (SWAP) {
#pragma unroll
        for (int m = 0; m < MR; ++m) {
            const int r = row0 + wrow * WRSPAN + m * 16 + lrow;
#pragma unroll
            for (int n = 0; n < 2; ++n) {
                const int c0 = col0 + wcol * 32 + n * 16 + lhalf * 4;
                const float4 bv = *(const float4*)(bias + c0);
                float o0 = acc[m][n][0] + bv.x, o1 = acc[m][n][1] + bv.y;
                float o2 = acc[m][n][2] + bv.z, o3 = acc[m][n][3] + bv.w;
                if (relu) {
                    o0 = fmaxf(o0, 0.f); o1 = fmaxf(o1, 0.f);
                    o2 = fmaxf(o2, 0.f); o3 = fmaxf(o3, 0.f);
                }
                if (OUTBF16) {
                    union { __bf16 h4[4]; u16x4 u; } pk;
                    pk.h4[0] = (__bf16)o0; pk.h4[1] = (__bf16)o1;
                    pk.h4[2] = (__bf16)o2; pk.h4[3] = (__bf16)o3;
                    *(u16x4*)((__bf16*)Cout + (size_t)r * MS + c0) = pk.u;
                } else {
                    *(float4*)((float*)Cout + (size_t)r * MS + c0) =
                        make_float4(o0, o1, o2, o3);
                }
            }
        }
    } else {
        const int orow = row0 + wrow * WRSPAN + lhalf * 4;
        const int ocol = col0 + wcol * 32 + lrow;
        const int smask = (1 << log2S) - 1;
#pragma unroll
        for (int n = 0; n < 2; ++n) {
            const int c = ocol + n * 16;
            if (c >= m_vt0) {
                const int cv = c - m_vt0;
                const int hh = cv >> 6, dd = cv & 63;
                const float bv = (bias2 && c >= bsplit) ? bias2[c - bsplit] : bias[c];
#pragma unroll
                for (int m = 0; m < MR; ++m) {
                    const int rr = orow + m * 16;
                    const int bb = rr >> log2S, ss = rr & smask;
                    union { __bf16 h4[4]; u16x4 u; } pk;
#pragma unroll
                    for (int j = 0; j < 4; ++j)
                        pk.h4[j] = (__bf16)(acc[m][n][j] + bv);
                    *(u16x4*)(VTout + (((size_t)((bb * 8 + hh) * 64 + dd)) << log2S) + ss) = pk.u;
                }
            } else if (c < Mlim) {
                const float bv = (bias2 && c >= bsplit) ? bias2[c - bsplit] : bias[c];
#pragma unroll
                for (int m = 0; m < MR; ++m) {
#pragma unroll
                    for (int j = 0; j < 4; ++j) {
                        int rr = orow + m * 16 + j;
                        if (permrow) rr = ((rr & smask) * BATCH) + (rr >> log2S);
                        float v = acc[m][n][j] + bv;
                        if (relu) v = fmaxf(v, 0.f);
                        if (OUTBF16) ((__bf16*)Cout)[(size_t)rr * MS + c] = (__bf16)v;
                        else         ((float*)Cout)[(size_t)rr * MS + c] = v;
                    }
                }
            }
        }
    }
}

// ---------------------------------------------------------------------------
// MFMA flash attention, [b][s][*] layout, double-buffered K/V staging.
// 1D grid + XCD swizzle: wg -> (qc = wg % nqc, hb = wg / nqc). The nqc
// qc-blocks sharing one (h,b)'s K/V stay consecutive -> same-XCD L2 reuse.
// setprio(1) around MFMA clusters (T5).
// ---------------------------------------------------------------------------
template <int CAUSAL>
__global__ __launch_bounds__(256) void attn_mfma(
    const __bf16* __restrict__ Qb, const __bf16* __restrict__ Kb,
    const __bf16* __restrict__ VT, __bf16* __restrict__ Op,
    int Sq, int Skv, int qstride, int kstride, int koff, float scale, int nqc)
{
    __shared__ __align__(16) char smem[40960];
    const int tid = threadIdx.x;
    const int l   = tid & 63;
    const int w   = tid >> 6;
    char* Psm = smem + 32768 + w * 2048;

    const int wg = xcd_swz(blockIdx.x, gridDim.x);
    const int qc = wg % nqc;
    const int hb = wg / nqc;
    const int h  = hb & 7;
    const int b  = hb >> 3;

    const int l15 = l & 15;
    const int g   = l >> 4;
    const int sw  = l15 & 7;

    const int sq = qc * 64 + w * 16 + l15;
    const __bf16* qrow = Qb + ((size_t)(b * Sq + sq)) * qstride + h * 64 + g * 8;
    const bf16x8 qf0 = *(const bf16x8*)(qrow);
    const bf16x8 qf1 = *(const bf16x8*)(qrow + 32);

    const int srow = tid >> 3;
    const int slot = tid & 7;

    auto stageKV = [&](char* buf, int kc) {
#pragma unroll
        for (int p = 0; p < 2; ++p) {
            const int r   = p * 32 + srow;
            const int sgo = (slot ^ (r & 7)) * 8;
            const __bf16* ksrc = Kb + ((size_t)(b * Skv + kc * 64 + r)) * kstride
                                    + koff + h * 64 + sgo;
            gload_lds16(ksrc, buf + (p * 256 + tid) * 16);
            const __bf16* vsrc = VT + ((size_t)((b * 8 + h) * 64 + r)) * Skv
                                    + kc * 64 + sgo;
            gload_lds16(vsrc, buf + 8192 + (p * 256 + tid) * 16);
        }
    };

    f32x4 acc[4] = {};
    float m_run = -1e30f, l_run = 0.f;

    const int nkc = CAUSAL ? (qc + 1) : (Skv >> 6);
    stageKV(smem, 0);
    int cur = 0;
    for (int kc = 0; kc < nkc; ++kc) {
        __syncthreads();
        if (kc + 1 < nkc) stageKV(smem + (cur ^ 1) * 16384, kc + 1);
        const char* Ksm = smem + cur * 16384;
        const char* Vsm = Ksm + 8192;

        f32x4 st[4];
        __builtin_amdgcn_s_setprio(1);
#pragma unroll
        for (int f = 0; f < 4; ++f) {
            const char* kr = Ksm + (f * 16 + l15) * 128;
            bf16x8 ka0 = *(const bf16x8*)(kr + ((g ^ sw) * 16));
            bf16x8 ka1 = *(const bf16x8*)(kr + (((4 + g) ^ sw) * 16));
            f32x4 z = {};
            z = __builtin_amdgcn_mfma_f32_16x16x32_bf16(ka0, qf0, z, 0, 0, 0);
            st[f] = __builtin_amdgcn_mfma_f32_16x16x32_bf16(ka1, qf1, z, 0, 0, 0);
        }
        __builtin_amdgcn_s_setprio(0);

        float rmax = -1e30f;
#pragma unroll
        for (int f = 0; f < 4; ++f)
#pragma unroll
            for (int j = 0; j < 4; ++j) {
                float v = st[f][j] * scale;
                if (CAUSAL) {
                    if (kc * 64 + f * 16 + g * 4 + j > sq) v = -1e30f;
                }
                st[f][j] = v;
                rmax = fmaxf(rmax, v);
            }
        rmax = fmaxf(rmax, __shfl_xor(rmax, 16, 64));
        rmax = fmaxf(rmax, __shfl_xor(rmax, 32, 64));
        const float mn = fmaxf(m_run, rmax);
        const float corr = __expf(m_run - mn);
        m_run = mn;
        float rsum = 0.f;
#pragma unroll
        for (int f = 0; f < 4; ++f)
#pragma unroll
            for (int j = 0; j < 4; ++j) {
                float p = __expf(st[f][j] - mn);
                st[f][j] = p;
                rsum += p;
            }
        rsum += __shfl_xor(rsum, 16, 64);
        rsum += __shfl_xor(rsum, 32, 64);
        l_run = l_run * corr + rsum;

#pragma unroll
        for (int j = 0; j < 4; ++j) {
            const float cj = __shfl(corr, g * 20 + j, 64);
            acc[0][j] *= cj; acc[1][j] *= cj; acc[2][j] *= cj; acc[3][j] *= cj;
        }

#pragma unroll
        for (int f = 0; f < 4; ++f)
#pragma unroll
            for (int j2 = 0; j2 < 2; ++j2) {
                union { __bf16 h2[2]; unsigned u; } cv;
                cv.h2[0] = (__bf16)st[f][2 * j2];
                cv.h2[1] = (__bf16)st[f][2 * j2 + 1];
                const int key0 = 16 * f + 4 * g + 2 * j2;
                const int byte = l15 * 128 + (((key0 >> 3) ^ sw) * 16) + (key0 & 7) * 2;
                *(unsigned*)(Psm + byte) = cv.u;
            }

        __builtin_amdgcn_s_setprio(1);
#pragma unroll
        for (int ks = 0; ks < 2; ++ks) {
            const int so = ((4 * ks + g) ^ sw) * 16;
            bf16x8 pa = *(const bf16x8*)(Psm + l15 * 128 + so);
#pragma unroll
            for (int n = 0; n < 4; ++n) {
                bf16x8 vb = *(const bf16x8*)(Vsm + (n * 16 + l15) * 128 + so);
                acc[n] = __builtin_amdgcn_mfma_f32_16x16x32_bf16(pa, vb, acc[n], 0, 0, 0);
            }
        }
        __builtin_amdgcn_s_setprio(0);
        cur ^= 1;
    }

    const float inv = 1.f / l_run;
#pragma unroll
    for (int j = 0; j < 4; ++j) {
        const float ij = __shfl(inv, g * 20 + j, 64);
        const int s = qc * 64 + w * 16 + g * 4 + j;
        __bf16* orow = Op + ((size_t)(b * Sq + s)) * D_MODEL + h * 64 + l15;
#pragma unroll
        for (int n = 0; n < 4; ++n)
            orow[n * 16] = (__bf16)(acc[n][j] * ij);
    }
}

// ---------------------------------------------------------------------------
// Residual add + LayerNorm: X fp32 + Y bf16 -> fp32 + bf16. One block/row.
// ---------------------------------------------------------------------------
__global__ __launch_bounds__(256) void add_ln(
    const float* __restrict__ X, const __bf16* __restrict__ Y,
    const float* __restrict__ w, const float* __restrict__ bias,
    float* __restrict__ Of, __bf16* __restrict__ Oh)
{
    const int t   = blockIdx.x;
    const int tid = threadIdx.x;
    const float2 x2 = *(const float2*)(X + (size_t)t * D_MODEL + tid * 2);
    const u16x2 yv = *(const u16x2*)(Y + (size_t)t * D_MODEL + tid * 2);
    union { u16x2 u; __bf16 h2[2]; } yc; yc.u = yv;
    float v0 = x2.x + (float)yc.h2[0], v1 = x2.y + (float)yc.h2[1];
    float sum = v0 + v1;
    float sq  = v0 * v0 + v1 * v1;
#pragma unroll
    for (int off = 32; off; off >>= 1) {
        sum += __shfl_xor(sum, off);
        sq  += __shfl_xor(sq, off);
    }
    __shared__ float ssum[4], ssq[4];
    const int wid = tid >> 6;
    if ((tid & 63) == 0) { ssum[wid] = sum; ssq[wid] = sq; }
    __syncthreads();
    sum = ssum[0] + ssum[1] + ssum[2] + ssum[3];
    sq  = ssq[0] + ssq[1] + ssq[2] + ssq[3];

    const float mu  = sum * (1.f / D_MODEL);
    const float var = sq * (1.f / D_MODEL) - mu * mu;
    const float rs  = rsqrtf(var + EPS_LN);
    const float2 w2 = *(const float2*)(w + tid * 2);
    const float2 b2 = *(const float2*)(bias + tid * 2);
    float o0 = (v0 - mu) * rs * w2.x + b2.x;
    float o1 = (v1 - mu) * rs * w2.y + b2.y;
    *(float2*)(Of + (size_t)t * D_MODEL + tid * 2) = make_float2(o0, o1);
    union { __bf16 h2[2]; u16x2 u; } cv;
    cv.h2[0] = (__bf16)o0; cv.h2[1] = (__bf16)o1;
    *(u16x2*)(Oh + (size_t)t * D_MODEL + tid * 2) = cv.u;
}

// ---------------------------------------------------------------------------
// src [s][b][512] -> permuted [b][s][512], fp32 + bf16.  grid = 8192.
// ---------------------------------------------------------------------------
__global__ __launch_bounds__(256) void permute_src(
    const float* __restrict__ src, float* __restrict__ Of, __bf16* __restrict__ Oh)
{
    const int t = blockIdx.x;
    const int b = t >> 9, s = t & 511;
    const int tid = threadIdx.x;
    const float2 v = *(const float2*)(src + ((size_t)(s * BATCH + b)) * D_MODEL + tid * 2);
    *(float2*)(Of + (size_t)t * D_MODEL + tid * 2) = v;
    union { __bf16 h2[2]; u16x2 u; } cv;
    cv.h2[0] = (__bf16)v.x; cv.h2[1] = (__bf16)v.y;
    *(u16x2*)(Oh + (size_t)t * D_MODEL + tid * 2) = cv.u;
}

// ---------------------------------------------------------------------------
// Token embedding + posenc -> [b][s][512], fp32 + bf16. One block per row.
// ---------------------------------------------------------------------------
__global__ __launch_bounds__(256) void embed_pos(
    const int* __restrict__ tokens, const float* __restrict__ emb,
    float* __restrict__ Of, __bf16* __restrict__ Oh)
{
    const int t   = blockIdx.x;
    const int b   = t >> 7, s = t & 127;
    const int tid = threadIdx.x;
    const int tok = tokens[s * BATCH + b];
    const float C = 9.210340371976184f / 256.f;
    const int d = tid * 2;
    const int j = (d < 256) ? d : (d - 256);
    float a0 = (float)s * expf(-(float)j * C);
    float a1 = (float)s * expf(-(float)(j + 1) * C);
    float pe0 = (d < 256) ? sinf(a0) : cosf(a0);
    float pe1 = (d < 256) ? sinf(a1) : cosf(a1);
    const float2 e2 = *(const float2*)(emb + (size_t)tok * D_MODEL + d);
    float o0 = e2.x + pe0, o1 = e2.y + pe1;
    *(float2*)(Of + (size_t)t * D_MODEL + d) = make_float2(o0, o1);
    union { __bf16 h2[2]; u16x2 u; } cv;
    cv.h2[0] = (__bf16)o0; cv.h2[1] = (__bf16)o1;
    *(u16x2*)(Oh + (size_t)t * D_MODEL + d) = cv.u;
}

// ---------------------------------------------------------------------------
// Multi-segment fp32 -> bf16 (12 segments). Monotonic walk; nontemporal
// loads (fp32 stream is never re-read -> keep it out of L2).
// ---------------------------------------------------------------------------
struct CvtSeg { const float* s; __bf16* d; int n8; };
struct CvtArgs { CvtSeg seg[12]; int tot8; };

__global__ __launch_bounds__(256) void cvt_multi(CvtArgs a)
{
    const int stride = gridDim.x * 256;
    int sgi = 0;
    int base = 0;
    for (int u = blockIdx.x * 256 + threadIdx.x; u < a.tot8; u += stride) {
        while (u - base >= a.seg[sgi].n8) { base += a.seg[sgi].n8; ++sgi; }
        const int v = u - base;
        const f32x4* sp = (const f32x4*)a.seg[sgi].s + (size_t)v * 2;
        const f32x4 f0 = __builtin_nontemporal_load(sp);
        const f32x4 f1 = __builtin_nontemporal_load(sp + 1);
        union { __bf16 h[8]; u16x8 u; } c;
        c.h[0] = (__bf16)f0[0]; c.h[1] = (__bf16)f0[1];
        c.h[2] = (__bf16)f0[2]; c.h[3] = (__bf16)f0[3];
        c.h[4] = (__bf16)f1[0]; c.h[5] = (__bf16)f1[1];
        c.h[6] = (__bf16)f1[2]; c.h[7] = (__bf16)f1[3];
        ((u16x8*)a.seg[sgi].d)[v] = c.u;
    }
}

__global__ __launch_bounds__(256) void pad_outw(
    const float* __restrict__ w, __bf16* __restrict__ o)
{
    const int idx = blockIdx.x * 256 + threadIdx.x;
    const int r = idx >> 9;
    const int c = idx & 511;
    o[idx] = (__bf16)(r < 97 ? w[r * 512 + c] : 0.f);
}

// ---------------------------------------------------------------------------
// Host orchestration
// ---------------------------------------------------------------------------
extern "C" void kernel_launch(void* const* d_in, const int* in_sizes, int n_in,
                              void* d_out, int out_size, void* d_ws, size_t ws_size,
                              hipStream_t stream)
{
    const float* src     = (const float*)d_in[0];
    const int*   tokens  = (const int*)d_in[1];
    const float* tok_emb = (const float*)d_in[2];
    const float* enc_qkv_w = (const float*)d_in[3];
    const float* enc_qkv_b = (const float*)d_in[4];
    const float* enc_out_w = (const float*)d_in[5];
    const float* enc_out_b = (const float*)d_in[6];
    const float* enc_l1_w  = (const float*)d_in[7];
    const float* enc_l1_b  = (const float*)d_in[8];
    const float* enc_l2_w  = (const float*)d_in[9];
    const float* enc_l2_b  = (const float*)d_in[10];
    const float* enc_n1_w  = (const float*)d_in[11];
    const float* enc_n1_b  = (const float*)d_in[12];
    const float* enc_n2_w  = (const float*)d_in[13];
    const float* enc_n2_b  = (const float*)d_in[14];
    const float* dec_qkv_w = (const float*)d_in[15];
    const float* dec_qkv_b = (const float*)d_in[16];
    const float* dec_sout_w = (const float*)d_in[17];
    const float* dec_sout_b = (const float*)d_in[18];
    const float* dec_q_w   = (const float*)d_in[19];
    const float* dec_q_b   = (const float*)d_in[20];
    const float* dec_k_w   = (const float*)d_in[21];
    const float* dec_k_b   = (const float*)d_in[22];
    const float* dec_v_w   = (const float*)d_in[23];
    const float* dec_v_b   = (const float*)d_in[24];
    const float* dec_cout_w = (const float*)d_in[25];
    const float* dec_cout_b = (const float*)d_in[26];
    const float* dec_l1_w  = (const float*)d_in[27];
    const float* dec_l1_b  = (const float*)d_in[28];
    const float* dec_l2_w  = (const float*)d_in[29];
    const float* dec_l2_b  = (const float*)d_in[30];
    const float* dec_n1_w  = (const float*)d_in[31];
    const float* dec_n1_b  = (const float*)d_in[32];
    const float* dec_n2_w  = (const float*)d_in[33];
    const float* dec_n2_b  = (const float*)d_in[34];
    const float* dec_n3_w  = (const float*)d_in[35];
    const float* dec_n3_b  = (const float*)d_in[36];
    const float* out_w     = (const float*)d_in[37];
    const float* out_b     = (const float*)d_in[38];

    const int NE = 512 * BATCH;   // 8192 rows, [b][s]
    const int ND = 128 * BATCH;   // 2048 rows, [b][s]
    const float scale = 0.125f;
    const int BIG = 1 << 30;

    // -------- workspace layout (bytes) --------
    char* w8 = (char*)d_ws;
    float*  Ax_f = (float*) (w8 + 0);          // 16 MB enc residual fp32
    float*  T_f  = (float*) (w8 + 16777216);   //  4 MB dec residual fp32
    __bf16* Ax_h = (__bf16*)(w8 + 20971520);   //  8 MB enc bf16
    __bf16* T_h  = (__bf16*)(w8 + 29360128);   //  2 MB dec bf16
    __bf16* AO_h = (__bf16*)(w8 + 31457280);   //  8 MB attn out bf16
    __bf16* Y_h  = (__bf16*)(w8 + 39845888);   //  8 MB residual-Y bf16
    __bf16* VT   = (__bf16*)(w8 + 48234496);   //  8 MB V-transpose
    __bf16* OWp  = (__bf16*)(w8 + 56623104);   //  0.13 MB padded out_w
    char*   Gb   = w8 + 56754176;              // 33.5 MB union
    __bf16* Gqk  = (__bf16*)Gb;                // qk bf16 [N][1024]
    __bf16* Gh   = (__bf16*)Gb;                // ffn hidden bf16 [N][2048]
    __bf16* Gq   = (__bf16*)Gb;                // cross q bf16 [2048][512]
    __bf16* Gk   = (__bf16*)(Gb + 2097152);    // cross k bf16 [8192][512]
    __bf16* WB   = (__bf16*)(w8 + 90308608);   // weights (88 MB upfront)

    const bool upfront = ws_size >= (size_t)178388992;

    auto gemmS = [&](const __bf16* Am, const __bf16* Wm, const float* bv,
                     void* C, int N, int M, int K, int relu) {
        const int nb128 = (M / 128) * (N / 128);
        const int gx = M / 128;
        if (nb128 >= 512) {
            gemm_mfma<128, 1, 1><<<gx * (N / 128), 512, 0, stream>>>(
                Am, Wm, nullptr, BIG, bv, nullptr, 0, C, nullptr, BIG, 0,
                gx, M, M, K, relu, 0);
        } else {
            gemm_mfma<64, 1, 1><<<gx * (N / 64), 512, 0, stream>>>(
                Am, Wm, nullptr, BIG, bv, nullptr, 0, C, nullptr, BIG, 0,
                gx, M, M, K, relu, 0);
        }
    };
    auto gemmN = [&](const __bf16* Am, const __bf16* Wm, const __bf16* W2m, int wsplit,
                     const float* bv, const float* bv2, int bsplit,
                     void* C, __bf16* VTp, int m_vt0, int log2S,
                     int N, int M, int MS, int K, bool outbf, int permrow) {
        const int gx = (M + 127) / 128;
        const int nb128 = gx * (N / 128);
        if (nb128 >= 512) {
            if (outbf) gemm_mfma<128, 1, 0><<<gx * (N / 128), 512, 0, stream>>>(
                Am, Wm, W2m, wsplit, bv, bv2, bsplit, C, VTp, m_vt0, log2S,
                gx, M, MS, K, 0, permrow);
            else       gemm_mfma<128, 0, 0><<<gx * (N / 128), 512, 0, stream>>>(
                Am, Wm, W2m, wsplit, bv, bv2, bsplit, C, VTp, m_vt0, log2S,
                gx, M, MS, K, 0, permrow);
        } else {
            if (outbf) gemm_mfma<64, 1, 0><<<gx * (N / 64), 512, 0, stream>>>(
                Am, Wm, W2m, wsplit, bv, bv2, bsplit, C, VTp, m_vt0, log2S,
                gx, M, MS, K, 0, permrow);
            else       gemm_mfma<64, 0, 0><<<gx * (N / 64), 512, 0, stream>>>(
                Am, Wm, W2m, wsplit, bv, bv2, bsplit, C, VTp, m_vt0, log2S,
                gx, M, MS, K, 0, permrow);
        }
    };
    auto cvt = [&](CvtArgs& a, int blocks) {
        int tot = 0;
        for (int i = 0; i < 12; ++i) tot += a.seg[i].n8;
        a.tot8 = tot;
        cvt_multi<<<blocks, 256, 0, stream>>>(a);
    };

    // ---- upfront: permute src, pad out_w, convert weights ----
    permute_src<<<NE, 256, 0, stream>>>(src, Ax_f, Ax_h);
    pad_outw<<<256, 256, 0, stream>>>(out_w, OWp);

    __bf16* WencQKV = WB;
    __bf16* WencOUT = WencQKV + 4718592;
    __bf16* WencL1  = WencOUT + 1572864;
    __bf16* WencL2  = WencL1 + 6291456;
    __bf16* WdecQKV = WencL2 + 6291456;
    __bf16* WdecSOUT = WdecQKV + 4718592;
    __bf16* WdecQ   = WdecSOUT + 1572864;
    __bf16* WdecK   = WdecQ + 1572864;
    __bf16* WdecV   = WdecK + 1572864;
    __bf16* WdecCOUT = WdecV + 1572864;
    __bf16* WdecL1  = WdecCOUT + 1572864;
    __bf16* WdecL2  = WdecL1 + 6291456;

    if (upfront) {
        CvtArgs a = {};
        a.seg[0]  = { enc_qkv_w,  WencQKV,  4718592 / 8 };
        a.seg[1]  = { enc_out_w,  WencOUT,  1572864 / 8 };
        a.seg[2]  = { enc_l1_w,   WencL1,   6291456 / 8 };
        a.seg[3]  = { enc_l2_w,   WencL2,   6291456 / 8 };
        a.seg[4]  = { dec_qkv_w,  WdecQKV,  4718592 / 8 };
        a.seg[5]  = { dec_sout_w, WdecSOUT, 1572864 / 8 };
        a.seg[6]  = { dec_q_w,    WdecQ,    1572864 / 8 };
        a.seg[7]  = { dec_k_w,    WdecK,    1572864 / 8 };
        a.seg[8]  = { dec_v_w,    WdecV,    1572864 / 8 };
        a.seg[9]  = { dec_cout_w, WdecCOUT, 1572864 / 8 };
        a.seg[10] = { dec_l1_w,   WdecL1,   6291456 / 8 };
        a.seg[11] = { dec_l2_w,   WdecL2,   6291456 / 8 };
        cvt(a, 4096);
    }

    // ---------------- Encoder ----------------
    for (int i = 0; i < 6; ++i) {
        __bf16 *wqkv, *wout, *wl1, *wl2;
        if (upfront) {
            wqkv = WencQKV + (size_t)i * 786432;
            wout = WencOUT + (size_t)i * 262144;
            wl1  = WencL1 + (size_t)i * 1048576;
            wl2  = WencL2 + (size_t)i * 1048576;
        } else {
            wqkv = WB; wout = WB + 786432; wl1 = WB + 1048576; wl2 = WB + 2097152;
            CvtArgs a = {};
            a.seg[0] = { enc_qkv_w + (size_t)i * 786432,  wqkv, 786432 / 8 };
            a.seg[1] = { enc_out_w + (size_t)i * 262144,  wout, 262144 / 8 };
            a.seg[2] = { enc_l1_w  + (size_t)i * 1048576, wl1, 1048576 / 8 };
            a.seg[3] = { enc_l2_w  + (size_t)i * 1048576, wl2, 1048576 / 8 };
            cvt(a, 1024);
        }

        gemmN(Ax_h, wqkv, nullptr, BIG, enc_qkv_b + (size_t)i * 1536, nullptr, 0,
              Gqk, VT, 1024, 9, NE, 1536, 1024, 512, true, 0);
        attn_mfma<0><<<8 * 8 * BATCH, 256, 0, stream>>>(
            Gqk, Gqk, VT, AO_h, 512, 512, 1024, 1024, 512, scale, 8);
        gemmS(AO_h, wout, enc_out_b + (size_t)i * 512, Y_h, NE, 512, 512, 0);
        add_ln<<<NE, 256, 0, stream>>>(Ax_f, Y_h,
                                       enc_n1_w + (size_t)i * 512, enc_n1_b + (size_t)i * 512,
                                       Ax_f, Ax_h);
        gemmS(Ax_h, wl1, enc_l1_b + (size_t)i * 2048, Gh, NE, 2048, 512, 1);
        gemmS(Gh, wl2, enc_l2_b + (size_t)i * 512, Y_h, NE, 512, 2048, 0);
        add_ln<<<NE, 256, 0, stream>>>(Ax_f, Y_h,
                                       enc_n2_w + (size_t)i * 512, enc_n2_b + (size_t)i * 512,
                                       Ax_f, Ax_h);
    }

    // ---------------- Decoder ----------------
    embed_pos<<<ND, 256, 0, stream>>>(tokens, tok_emb, T_f, T_h);
    for (int i = 0; i < 6; ++i) {
        __bf16 *dqkv, *dsout, *dq, *dk, *dv, *dcout, *dl1, *dl2;
        if (upfront) {
            dqkv  = WdecQKV + (size_t)i * 786432;
            dsout = WdecSOUT + (size_t)i * 262144;
            dq    = WdecQ + (size_t)i * 262144;
            dk    = WdecK + (size_t)i * 262144;
            dv    = WdecV + (size_t)i * 262144;
            dcout = WdecCOUT + (size_t)i * 262144;
            dl1   = WdecL1 + (size_t)i * 1048576;
            dl2   = WdecL2 + (size_t)i * 1048576;
        } else {
            dqkv = WB; dsout = WB + 786432; dq = WB + 1048576; dk = WB + 1310720;
            dv = WB + 1572864; dcout = WB + 1835008; dl1 = WB + 2097152; dl2 = WB + 3145728;
            CvtArgs a = {};
            a.seg[0] = { dec_qkv_w  + (size_t)i * 786432,  dqkv,  786432 / 8 };
            a.seg[1] = { dec_sout_w + (size_t)i * 262144,  dsout, 262144 / 8 };
            a.seg[2] = { dec_q_w    + (size_t)i * 262144,  dq,    262144 / 8 };
            a.seg[3] = { dec_k_w    + (size_t)i * 262144,  dk,    262144 / 8 };
            a.seg[4] = { dec_v_w    + (size_t)i * 262144,  dv,    262144 / 8 };
            a.seg[5] = { dec_cout_w + (size_t)i * 262144,  dcout, 262144 / 8 };
            a.seg[6] = { dec_l1_w   + (size_t)i * 1048576, dl1,  1048576 / 8 };
            a.seg[7] = { dec_l2_w   + (size_t)i * 1048576, dl2,  1048576 / 8 };
            cvt(a, 1024);
        }

        // causal self-attn
        gemmN(T_h, dqkv, nullptr, BIG, dec_qkv_b + (size_t)i * 1536, nullptr, 0,
              Gqk, VT, 1024, 7, ND, 1536, 1024, 512, true, 0);
        attn_mfma<1><<<2 * 8 * BATCH, 256, 0, stream>>>(
            Gqk, Gqk, VT, AO_h, 128, 128, 1024, 1024, 512, scale, 2);
        gemmS(AO_h, dsout, dec_sout_b + (size_t)i * 512, Y_h, ND, 512, 512, 0);
        add_ln<<<ND, 256, 0, stream>>>(T_f, Y_h,
                                       dec_n1_w + (size_t)i * 512, dec_n1_b + (size_t)i * 512,
                                       T_f, T_h);
        // cross-attn
        gemmS(T_h, dq, dec_q_b + (size_t)i * 512, Gq, ND, 512, 512, 0);
        gemmN(Ax_h, dk, dv, 512, dec_k_b + (size_t)i * 512, dec_v_b + (size_t)i * 512, 512,
              Gk, VT, 512, 9, NE, 1024, 512, 512, true, 0);
        attn_mfma<0><<<2 * 8 * BATCH, 256, 0, stream>>>(
            Gq, Gk, VT, AO_h, 128, 512, 512, 512, 0, scale, 2);
        gemmS(AO_h, dcout, dec_cout_b + (size_t)i * 512, Y_h, ND, 512, 512, 0);
        add_ln<<<ND, 256, 0, stream>>>(T_f, Y_h,
                                       dec_n2_w + (size_t)i * 512, dec_n2_b + (size_t)i * 512,
                                       T_f, T_h);
        // FFN
        gemmS(T_h, dl1, dec_l1_b + (size_t)i * 2048, Gh, ND, 2048, 512, 1);
        gemmS(Gh, dl2, dec_l2_b + (size_t)i * 512, Y_h, ND, 512, 2048, 0);
        add_ln<<<ND, 256, 0, stream>>>(T_f, Y_h,
                                       dec_n3_w + (size_t)i * 512, dec_n3_b + (size_t)i * 512,
                                       T_f, T_h);
    }

    // ---------------- Output projection (rows permuted back to [s][b]) ----
    gemmN(T_h, OWp, nullptr, BIG, out_b, nullptr, 0,
          (float*)d_out, nullptr, BIG, 7, ND, 97, 97, 512, false, 1);
}